// Round 12
// baseline (229.491 us; speedup 1.0000x reference)
//
#include <hip/hip_runtime.h>
#include <math.h>

#define NH 16
#define HD 64
#define HID 1024
#define SEQ 2048
#define NB 2

typedef __attribute__((ext_vector_type(8))) short short8;
typedef __attribute__((ext_vector_type(4))) float f32x4;
typedef unsigned short u16;
typedef unsigned int u32;

constexpr float LN_EPS_C = 1e-5f;
constexpr float SM_SCALE = 0.07216878364870323f; // 1/sqrt(64*3)

__device__ inline u16 f2b(float f) {
  unsigned u = __builtin_bit_cast(unsigned, f);
  u = (u + 0x7FFFu + ((u >> 16) & 1u)) >> 16;
  return (u16)u;
}
__device__ inline float b2f(u16 h) {
  unsigned u = ((unsigned)h) << 16;
  return __builtin_bit_cast(float, u);
}
__device__ inline u32 pk2(float lo, float hi) {
  return (u32)f2b(lo) | ((u32)f2b(hi) << 16);
}
__device__ inline f32x4 mfma16(short8 a, short8 b, f32x4 c) {
  return __builtin_amdgcn_mfma_f32_16x16x32_bf16(a, b, c, 0, 0, 0);
}
// swizzled read of a [rows][64] bf16 tile whose writes used slot = chunk^(row&7)
__device__ inline short8 swz8(const u16* base, int row, int hc) {
  return *reinterpret_cast<const short8*>(&base[row * 64 + 8 * (hc ^ (row & 7))]);
}
// add-rotate swizzle for [64 row][72-stride] tiles, col in [0,64).
__device__ inline int vrot(int row, int col) {
  return row * 72 + ((col + 16 * ((row >> 3) & 3)) & 63);
}
// DPP row-rotate reduction within the 16-lane row group
template <int N>
__device__ inline float rorf(float x) {
  return __builtin_bit_cast(float,
      __builtin_amdgcn_update_dpp(0, __builtin_bit_cast(int, x),
                                  0x120 + N, 0xF, 0xF, true));
}
__device__ inline float rmax16(float x) {
  x = fmaxf(x, rorf<1>(x)); x = fmaxf(x, rorf<2>(x));
  x = fmaxf(x, rorf<4>(x)); x = fmaxf(x, rorf<8>(x));
  return x;
}
__device__ inline float rsum16(float x) {
  x += rorf<1>(x); x += rorf<2>(x); x += rorf<4>(x); x += rorf<8>(x);
  return x;
}

// ---------------- LayerNorm over relpos_table rows -> bf16 ----------------
__global__ __launch_bounds__(256) void ln_kernel(const float* __restrict__ tbl,
    const float* __restrict__ gamma, const float* __restrict__ beta,
    u16* __restrict__ e) {
  int row = blockIdx.x;
  int t = threadIdx.x;
  const float4* rp = reinterpret_cast<const float4*>(tbl + (size_t)row * HID);
  float4 x = rp[t];
  float s = x.x + x.y + x.z + x.w;
  float ss = x.x * x.x + x.y * x.y + x.z * x.z + x.w * x.w;
  #pragma unroll
  for (int o = 1; o < 64; o <<= 1) {
    s += __shfl_xor(s, o);
    ss += __shfl_xor(ss, o);
  }
  __shared__ float sb[4], ssb[4];
  int w = t >> 6;
  if ((t & 63) == 0) { sb[w] = s; ssb[w] = ss; }
  __syncthreads();
  s = sb[0] + sb[1] + sb[2] + sb[3];
  ss = ssb[0] + ssb[1] + ssb[2] + ssb[3];
  float mu = s * (1.0f / HID);
  float var = ss * (1.0f / HID) - mu * mu;
  float rs = rsqrtf(var + LN_EPS_C);
  float4 g = reinterpret_cast<const float4*>(gamma)[t];
  float4 bt = reinterpret_cast<const float4*>(beta)[t];
  ushort4 o4;
  o4.x = f2b((x.x - mu) * rs * g.x + bt.x);
  o4.y = f2b((x.y - mu) * rs * g.y + bt.y);
  o4.z = f2b((x.z - mu) * rs * g.z + bt.z);
  o4.w = f2b((x.w - mu) * rs * g.w + bt.w);
  *reinterpret_cast<ushort4*>(&e[(size_t)row * HID + t * 4]) = o4;
}

// ---------------- f32 -> bf16 convert ----------------
__global__ __launch_bounds__(256) void conv_bf16(const float* __restrict__ src,
    u16* __restrict__ dst, int n) {
  int i = (blockIdx.x * 256 + threadIdx.x) * 8;
  if (i >= n) return;
  float4 a = *reinterpret_cast<const float4*>(&src[i]);
  float4 c = *reinterpret_cast<const float4*>(&src[i + 4]);
  short8 o;
  o[0] = (short)f2b(a.x); o[1] = (short)f2b(a.y); o[2] = (short)f2b(a.z); o[3] = (short)f2b(a.w);
  o[4] = (short)f2b(c.x); o[5] = (short)f2b(c.y); o[6] = (short)f2b(c.z); o[7] = (short)f2b(c.w);
  *reinterpret_cast<short8*>(&dst[i]) = o;
}

// ---------------- all 6 weight transposes in one launch ----------------
struct P6 {
  const float* s[6];
  u16* d[6];
};
__global__ __launch_bounds__(256) void transp_all(P6 p) {
  __shared__ float T[32][33];
  const float* W = p.s[blockIdx.z];
  u16* Wt = p.d[blockIdx.z];
  int bn = blockIdx.x * 32, bk = blockIdx.y * 32;
  int t = threadIdx.x;
  int r = t >> 3, c4 = (t & 7) * 4;
  float4 v = *reinterpret_cast<const float4*>(&W[(size_t)(bk + r) * HID + bn + c4]);
  T[r][c4 + 0] = v.x; T[r][c4 + 1] = v.y; T[r][c4 + 2] = v.z; T[r][c4 + 3] = v.w;
  __syncthreads();
  int n = t >> 3, k4 = (t & 7) * 4;
  ushort4 o;
  o.x = f2b(T[k4 + 0][n]); o.y = f2b(T[k4 + 1][n]);
  o.z = f2b(T[k4 + 2][n]); o.w = f2b(T[k4 + 3][n]);
  *reinterpret_cast<ushort4*>(&Wt[(size_t)(bn + n) * HID + bk + k4]) = o;
}

// ---------------- bf16 MFMA GEMM: 512 threads, 128x128, BK=64, multi-output ----------------
struct GO {
  const float* bias[3];
  void* out[3];
};
template <bool F32OUT>
__global__ __launch_bounds__(512) void gemm_bf16(const u16* __restrict__ A,
    const u16* __restrict__ Bt, GO go) {
  __shared__ u16 Al[8192]; // [128][64] swizzled
  __shared__ u16 Bl[8192];
  int t = threadIdx.x;
  int cb = blockIdx.x * 128, rb = blockIdx.y * 128;
  int which = cb >> 10, cbl = cb & 1023;
  const float* bias = go.bias[which];
  void* Cout = go.out[which];
  int wv = t >> 6, lane = t & 63, l15 = lane & 15, lg = lane >> 4;
  int wr = (wv >> 2) * 64, wc = (wv & 3) * 32;
  int srow = t >> 2, sch = t & 3;
  f32x4 acc[4][2];
  #pragma unroll
  for (int i = 0; i < 4; ++i)
    #pragma unroll
    for (int j = 0; j < 2; ++j) acc[i][j] = (f32x4){0.f, 0.f, 0.f, 0.f};
  const u16* Ap = A + (size_t)(rb + srow) * HID;
  const u16* Bp = Bt + (size_t)(cb + srow) * HID;
  int slot0 = 8 * (sch ^ (srow & 7));
  int slot1 = 8 * ((sch + 4) ^ (srow & 7));
  short8 pa0 = *reinterpret_cast<const short8*>(&Ap[sch * 8]);
  short8 pa1 = *reinterpret_cast<const short8*>(&Ap[(sch + 4) * 8]);
  short8 pb0 = *reinterpret_cast<const short8*>(&Bp[sch * 8]);
  short8 pb1 = *reinterpret_cast<const short8*>(&Bp[(sch + 4) * 8]);
  for (int kk = 0; kk < HID; kk += 64) {
    __syncthreads();
    *reinterpret_cast<short8*>(&Al[srow * 64 + slot0]) = pa0;
    *reinterpret_cast<short8*>(&Al[srow * 64 + slot1]) = pa1;
    *reinterpret_cast<short8*>(&Bl[srow * 64 + slot0]) = pb0;
    *reinterpret_cast<short8*>(&Bl[srow * 64 + slot1]) = pb1;
    __syncthreads();
    if (kk + 64 < HID) {
      pa0 = *reinterpret_cast<const short8*>(&Ap[kk + 64 + sch * 8]);
      pa1 = *reinterpret_cast<const short8*>(&Ap[kk + 64 + (sch + 4) * 8]);
      pb0 = *reinterpret_cast<const short8*>(&Bp[kk + 64 + sch * 8]);
      pb1 = *reinterpret_cast<const short8*>(&Bp[kk + 64 + (sch + 4) * 8]);
    }
    #pragma unroll
    for (int s = 0; s < 2; ++s) {
      short8 am[4], bn[2];
      #pragma unroll
      for (int i = 0; i < 4; ++i) am[i] = swz8(Al, wr + i * 16 + l15, s * 4 + lg);
      #pragma unroll
      for (int j = 0; j < 2; ++j) bn[j] = swz8(Bl, wc + j * 16 + l15, s * 4 + lg);
      #pragma unroll
      for (int i = 0; i < 4; ++i)
        #pragma unroll
        for (int j = 0; j < 2; ++j)
          acc[i][j] = mfma16(am[i], bn[j], acc[i][j]);
    }
  }
  #pragma unroll
  for (int j = 0; j < 2; ++j) {
    float bv = bias[cbl + wc + j * 16 + l15];
    #pragma unroll
    for (int i = 0; i < 4; ++i) {
      #pragma unroll
      for (int r = 0; r < 4; ++r) {
        size_t idx = (size_t)(rb + wr + i * 16 + lg * 4 + r) * HID + cbl + wc + j * 16 + l15;
        float v = acc[i][j][r] + bv;
        if (F32OUT) reinterpret_cast<float*>(Cout)[idx] = v;
        else reinterpret_cast<u16*>(Cout)[idx] = f2b(v);
      }
    }
  }
}

// ---------------- rank-1 bias precompute (PRESCALED) ----------------
__global__ __launch_bounds__(256) void biasqk(const u16* __restrict__ Qb,
    const u16* __restrict__ Kb, const u16* __restrict__ RKb,
    const u16* __restrict__ RQb, float* __restrict__ qrk0,
    float* __restrict__ krq0) {
  int o = blockIdx.x * 64 + (threadIdx.x >> 2);
  int sub = threadIdx.x & 3;
  int b = o >> 15, h = (o >> 11) & 15, i = o & 2047;
  size_t rbase = (size_t)(b * SEQ + i) * HID + h * HD + sub * 16;
  size_t tbase = (size_t)h * HD + sub * 16;
  float s1 = 0.f, s2 = 0.f;
  #pragma unroll
  for (int c = 0; c < 2; ++c) {
    short8 qv = *reinterpret_cast<const short8*>(&Qb[rbase + c * 8]);
    short8 rv = *reinterpret_cast<const short8*>(&RKb[tbase + c * 8]);
    short8 kv = *reinterpret_cast<const short8*>(&Kb[rbase + c * 8]);
    short8 uv = *reinterpret_cast<const short8*>(&RQb[tbase + c * 8]);
    #pragma unroll
    for (int j = 0; j < 8; ++j) {
      s1 += b2f((u16)qv[j]) * b2f((u16)rv[j]);
      s2 += b2f((u16)kv[j]) * b2f((u16)uv[j]);
    }
  }
  s1 += __shfl_xor(s1, 1); s1 += __shfl_xor(s1, 2);
  s2 += __shfl_xor(s2, 1); s2 += __shfl_xor(s2, 2);
  if (sub == 0) { qrk0[o] = s1 * SM_SCALE; krq0[o] = s2 * SM_SCALE; }
}

// ---------------- band bias precompute -> per-tile thread-ordered layout (PRESCALED) ----------------
__global__ __launch_bounds__(256, 3) void bias_kernel(
    const u16* __restrict__ Qb, const u16* __restrict__ Kb,
    const u16* __restrict__ RKb, const u16* __restrict__ RQb,
    u16* __restrict__ bandT) {
  __shared__ u16 smem[20992]; // 41984 B -> 3 blocks/CU
  const int KsO = 0, UO = 4096;
  const int RKO = UO, RQO = UO + 8192;
  const int G1O = UO, G2O = UO + 8448;

  int qt = blockIdx.x;
  int h = blockIdx.y, b = blockIdx.z;
  int q0 = qt * 64;
  int t = threadIdx.x;
  int wv = t >> 6, lane = t & 63, l15 = lane & 15, lg = lane >> 4;
  int qs = q0 + wv * 16;
  int hoff = h * HD;

  size_t qgrow = (size_t)(b * SEQ + qs + l15) * HID + hoff;
  short8 aq0 = *reinterpret_cast<const short8*>(&Qb[qgrow + lg * 8]);
  short8 aq1 = *reinterpret_cast<const short8*>(&Qb[qgrow + 32 + lg * 8]);

  const f32x4 Z = (f32x4){0.f, 0.f, 0.f, 0.f};
  int vr = t >> 2, vc8 = (t & 3) * 8;
  int ktlo = qt - 8; if (ktlo < 0) ktlo = 0;
  size_t tbase = (((size_t)(b * NH + h) * 32 + qt) * 9) << 12;

  for (int kt = ktlo; kt <= qt; ++kt) {
    int k0 = kt * 64;
    int dt = qt - kt;
    int wlo = 448 - 64 * dt; if (wlo < 0) wlo = 0;
    __syncthreads(); // #1: previous iteration's gathers done
    {
      const u16* kg = &Kb[(size_t)(b * SEQ + k0 + vr) * HID + hoff];
      int c0 = vc8 >> 3;
      *reinterpret_cast<short8*>(&smem[KsO + vr * 64 + 8 * (c0 ^ (vr & 7))]) =
          *reinterpret_cast<const short8*>(&kg[vc8]);
      *reinterpret_cast<short8*>(&smem[KsO + vr * 64 + 8 * ((c0 + 4) ^ (vr & 7))]) =
          *reinterpret_cast<const short8*>(&kg[vc8 + 32]);
    }
    for (int e2 = t; e2 < 1024; e2 += 256) {
      int rr = e2 >> 3, cch = e2 & 7;
      int wr2 = wlo + rr; if (wr2 > 511) wr2 = 511;
      size_t gb = (size_t)wr2 * HID + hoff + cch * 8;
      int slot = 8 * (cch ^ (rr & 7));
      *reinterpret_cast<short8*>(&smem[RKO + rr * 64 + slot]) =
          *reinterpret_cast<const short8*>(&RKb[gb]);
      *reinterpret_cast<short8*>(&smem[RQO + rr * 64 + slot]) =
          *reinterpret_cast<const short8*>(&RQb[gb]);
    }
    __syncthreads(); // #2: staging visible
    u32 g1p[16], g2p[16];
    #pragma unroll
    for (int cw = 0; cw < 8; ++cw) {
      short8 r0 = swz8(&smem[RKO], cw * 16 + l15, lg);
      short8 r1 = swz8(&smem[RKO], cw * 16 + l15, 4 + lg);
      f32x4 g = mfma16(r1, aq1, mfma16(r0, aq0, Z));
      g1p[2 * cw] = pk2(g[0], g[1]);
      g1p[2 * cw + 1] = pk2(g[2], g[3]);
    }
    short8 kw0 = swz8(&smem[KsO], wv * 16 + l15, lg);
    short8 kw1 = swz8(&smem[KsO], wv * 16 + l15, 4 + lg);
    #pragma unroll
    for (int cw = 0; cw < 8; ++cw) {
      short8 u0 = swz8(&smem[RQO], cw * 16 + l15, lg);
      short8 u1 = swz8(&smem[RQO], cw * 16 + l15, 4 + lg);
      f32x4 g = mfma16(u1, kw1, mfma16(u0, kw0, Z));
      g2p[2 * cw] = pk2(g[0], g[1]);
      g2p[2 * cw + 1] = pk2(g[2], g[3]);
    }
    __syncthreads(); // #3: band reads done; U reusable for G
    #pragma unroll
    for (int cw = 0; cw < 8; ++cw) {
      *reinterpret_cast<uint2*>(&smem[G1O + (wv * 16 + l15) * 132 + cw * 16 + lg * 4]) =
          make_uint2(g1p[2 * cw], g1p[2 * cw + 1]);
      *reinterpret_cast<uint2*>(&smem[G2O + (wv * 16 + l15) * 132 + cw * 16 + lg * 4]) =
          make_uint2(g2p[2 * cw], g2p[2 * cw + 1]);
    }
    __syncthreads(); // #4: G visible
    u16* outp = bandT + tbase + ((size_t)dt << 12) + t * 16;
    #pragma unroll
    for (int c = 0; c < 4; ++c) {
      float vv[4];
      #pragma unroll
      for (int r = 0; r < 4; ++r) {
        int q = qs + lg * 4 + r;
        int k = k0 + c * 16 + l15;
        int wi = 511 - (q - k) - wlo; if (wi < 0) wi = 0;
        vv[r] = (b2f(smem[G1O + (wv * 16 + lg * 4 + r) * 132 + wi]) +
                 b2f(smem[G2O + (c * 16 + l15) * 132 + wi])) * SM_SCALE;
      }
      *reinterpret_cast<uint2*>(outp + c * 4) =
          make_uint2(pk2(vv[0], vv[1]), pk2(vv[2], vv[3]));
    }
  }
}

// ---------------- fused DeBERTa flash attention: split-K over blocks ----------------
// blockIdx.x = pr*2+s: pair (qtA=31-pr heavy, qtB=pr light), parity s k-tiles only
// (kt = s, s+2, ...). Round-10-proven inner loop (stride 2). Writes f32 partials
// (O[64][64], m[64], l[64]) per (qt, s); merged by attn_merge. No inter-block sync.
__global__ __launch_bounds__(256, 2) void attn_mfma(
    const u16* __restrict__ Qb, const u16* __restrict__ Kb,
    const u16* __restrict__ Vb, const float* __restrict__ qrk0,
    const float* __restrict__ krq0, const u16* __restrict__ bandT,
    float* __restrict__ part) {
  __shared__ u16 smem[22016];
  const int KsB[2] = {0, 4096};
  const int VtB[2] = {8192, 12800};
  const int PsO = 17408;

  int pr = (int)blockIdx.x >> 1;
  int sp = (int)blockIdx.x & 1;
  int qtA = 31 - pr;
  int qtB = pr;
  int h = blockIdx.y, b = blockIdx.z;
  int t = threadIdx.x;
  int wv = t >> 6, lane = t & 63, l15 = lane & 15, lg = lane >> 4;
  int hoff = h * HD;
  int bh = (b * NH + h) * SEQ;
  size_t tbaseA = (((size_t)(b * NH + h) * 32 + qtA) * 9) << 12;
  size_t tbaseB = (((size_t)(b * NH + h) * 32 + qtB) * 9) << 12;

  int qsA = qtA * 64 + wv * 16;
  int qsB = qtB * 64 + wv * 16;
  size_t qgA = (size_t)(b * SEQ + qsA + l15) * HID + hoff;
  size_t qgB = (size_t)(b * SEQ + qsB + l15) * HID + hoff;
  short8 aqA0 = *reinterpret_cast<const short8*>(&Qb[qgA + lg * 8]);
  short8 aqA1 = *reinterpret_cast<const short8*>(&Qb[qgA + 32 + lg * 8]);
  short8 aqB0 = *reinterpret_cast<const short8*>(&Qb[qgB + lg * 8]);
  short8 aqB1 = *reinterpret_cast<const short8*>(&Qb[qgB + 32 + lg * 8]);
  float qb0A[4], qb0B[4];
  #pragma unroll
  for (int r = 0; r < 4; ++r) {
    qb0A[r] = qrk0[bh + qsA + lg * 4 + r];
    qb0B[r] = qrk0[bh + qsB + lg * 4 + r];
  }

  float mA[4], lA[4], mB[4], lB[4];
  f32x4 oA[4], oB[4];
  #pragma unroll
  for (int r = 0; r < 4; ++r) { mA[r] = -INFINITY; lA[r] = 0.f; mB[r] = -INFINITY; lB[r] = 0.f; }
  #pragma unroll
  for (int c = 0; c < 4; ++c) {
    oA[c] = (f32x4){0.f, 0.f, 0.f, 0.f};
    oB[c] = (f32x4){0.f, 0.f, 0.f, 0.f};
  }

  const f32x4 Z = (f32x4){0.f, 0.f, 0.f, 0.f};
  int vr = t >> 2, vc8 = (t & 3) * 8;
  int c0s = vc8 >> 3;
  int kslot0 = vr * 64 + 8 * (c0s ^ (vr & 7));
  int kslot1 = vr * 64 + 8 * ((c0s + 4) ^ (vr & 7));
  int vslot[16];
  #pragma unroll
  for (int j = 0; j < 8; ++j) {
    vslot[j] = vrot(vc8 + j, vr);
    vslot[8 + j] = vrot(vc8 + 32 + j, vr);
  }

  // ---- prologue: stage tile sp into buffer 0 (tile sp always exists: qtA>=16) ----
  {
    const u16* kg = &Kb[(size_t)(b * SEQ + sp * 64 + vr) * HID + hoff];
    short8 k0v = *reinterpret_cast<const short8*>(&kg[vc8]);
    short8 k1v = *reinterpret_cast<const short8*>(&kg[vc8 + 32]);
    *reinterpret_cast<short8*>(&smem[KsB[0] + kslot0]) = k0v;
    *reinterpret_cast<short8*>(&smem[KsB[0] + kslot1]) = k1v;
    const u16* vg = &Vb[(size_t)(b * SEQ + sp * 64 + vr) * HID + hoff];
    short8 v0v = *reinterpret_cast<const short8*>(&vg[vc8]);
    short8 v1v = *reinterpret_cast<const short8*>(&vg[vc8 + 32]);
    #pragma unroll
    for (int j = 0; j < 8; ++j) smem[VtB[0] + vslot[j]] = (u16)v0v[j];
    #pragma unroll
    for (int j = 0; j < 8; ++j) smem[VtB[0] + vslot[8 + j]] = (u16)v1v[j];
  }
  __syncthreads();

  int cur = 0;
  for (int kt = sp; kt <= qtA; kt += 2) {
    int k0 = kt * 64;
    int dtA = qtA - kt;
    bool doB = (kt <= qtB);
    int dtB = qtB - kt;
    bool bandedA = (dtA <= 8);
    bool bandedB = doB && (dtB <= 8);
    int ksb = KsB[cur], vtb = VtB[cur];
    int ksn = KsB[cur ^ 1], vtn = VtB[cur ^ 1];

    // ---- early loads: bias tiles (coalesced), kq when needed, next K/V prefetch ----
    short8 pA0, pA1, pB0, pB1;
    if (bandedA) {
      const u16* tb = bandT + tbaseA + ((size_t)dtA << 12) + t * 16;
      pA0 = *reinterpret_cast<const short8*>(tb);
      pA1 = *reinterpret_cast<const short8*>(tb + 8);
    }
    if (bandedB) {
      const u16* tb = bandT + tbaseB + ((size_t)dtB << 12) + t * 16;
      pB0 = *reinterpret_cast<const short8*>(tb);
      pB1 = *reinterpret_cast<const short8*>(tb + 8);
    }
    float kq[4];
    if (dtA > 8 || (doB && dtB > 8)) {
      #pragma unroll
      for (int c = 0; c < 4; ++c) kq[c] = krq0[bh + k0 + c * 16 + l15];
    }
    short8 nk0, nk1, nv0, nv1;
    if (kt + 2 <= qtA) {
      const u16* kg = &Kb[(size_t)(b * SEQ + k0 + 128 + vr) * HID + hoff];
      nk0 = *reinterpret_cast<const short8*>(&kg[vc8]);
      nk1 = *reinterpret_cast<const short8*>(&kg[vc8 + 32]);
      const u16* vg = &Vb[(size_t)(b * SEQ + k0 + 128 + vr) * HID + hoff];
      nv0 = *reinterpret_cast<const short8*>(&vg[vc8]);
      nv1 = *reinterpret_cast<const short8*>(&vg[vc8 + 32]);
    }

    // ---- K fragments (shared by A and B) ----
    short8 kb0[4], kb1[4];
    #pragma unroll
    for (int c = 0; c < 4; ++c) {
      kb0[c] = swz8(&smem[ksb], c * 16 + l15, lg);
      kb1[c] = swz8(&smem[ksb], c * 16 + l15, 4 + lg);
    }
    f32x4 sA[4], sB[4];
    #pragma unroll
    for (int c = 0; c < 4; ++c)
      sA[c] = mfma16(aqA1, kb1[c], mfma16(aqA0, kb0[c], Z));
    if (doB) {
      #pragma unroll
      for (int c = 0; c < 4; ++c)
        sB[c] = mfma16(aqB1, kb1[c], mfma16(aqB0, kb0[c], Z));
    }
    // ---- bias (prescaled) + fma-scale + mask ----
    #pragma unroll
    for (int c = 0; c < 4; ++c) {
      #pragma unroll
      for (int r = 0; r < 4; ++r) {
        float bbv = bandedA ? b2f((u16)((c < 2 ? pA0 : pA1)[(c & 1) * 4 + r]))
                            : qb0A[r] + kq[c];
        float v = fmaf(sA[c][r], SM_SCALE, bbv);
        if (dtA == 0) {
          int ql = wv * 16 + lg * 4 + r, kl = c * 16 + l15;
          if (ql < kl) v = -INFINITY;
        }
        sA[c][r] = v;
      }
    }
    if (doB) {
      #pragma unroll
      for (int c = 0; c < 4; ++c) {
        #pragma unroll
        for (int r = 0; r < 4; ++r) {
          float bbv = bandedB ? b2f((u16)((c < 2 ? pB0 : pB1)[(c & 1) * 4 + r]))
                              : qb0B[r] + kq[c];
          float v = fmaf(sB[c][r], SM_SCALE, bbv);
          if (dtB == 0) {
            int ql = wv * 16 + lg * 4 + r, kl = c * 16 + l15;
            if (ql < kl) v = -INFINITY;
          }
          sB[c][r] = v;
        }
      }
    }
    // ---- softmax (DPP row reductions; two independent chains) ----
    float alA[4], alB[4];
    #pragma unroll
    for (int r = 0; r < 4; ++r) {
      float mx = fmaxf(fmaxf(sA[0][r], sA[1][r]), fmaxf(sA[2][r], sA[3][r]));
      mx = rmax16(mx);
      float mn = fmaxf(mA[r], mx);
      alA[r] = __expf(mA[r] - mn);
      float ps = 0.f;
      #pragma unroll
      for (int c = 0; c < 4; ++c) {
        float p = __expf(sA[c][r] - mn);
        sA[c][r] = p;
        ps += p;
      }
      ps = rsum16(ps);
      lA[r] = lA[r] * alA[r] + ps;
      mA[r] = mn;
    }
    if (doB) {
      #pragma unroll
      for (int r = 0; r < 4; ++r) {
        float mx = fmaxf(fmaxf(sB[0][r], sB[1][r]), fmaxf(sB[2][r], sB[3][r]));
        mx = rmax16(mx);
        float mn = fmaxf(mB[r], mx);
        alB[r] = __expf(mB[r] - mn);
        float ps = 0.f;
        #pragma unroll
        for (int c = 0; c < 4; ++c) {
          float p = __expf(sB[c][r] - mn);
          sB[c][r] = p;
          ps += p;
        }
        ps = rsum16(ps);
        lB[r] = lB[r] * alB[r] + ps;
        mB[r] = mn;
      }
    }
    // ---- V fragments (shared) ----
    short8 vb0[4], vb1[4];
    #pragma unroll
    for (int c = 0; c < 4; ++c) {
      int n = c * 16 + l15;
      vb0[c] = *reinterpret_cast<const short8*>(&smem[vtb + vrot(n, lg * 8)]);
      vb1[c] = *reinterpret_cast<const short8*>(&smem[vtb + vrot(n, 32 + lg * 8)]);
    }
    // ---- PV A ----
    #pragma unroll
    for (int c = 0; c < 4; ++c) {
      #pragma unroll
      for (int r = 0; r < 4; ++r) {
        smem[PsO + vrot(wv * 16 + lg * 4 + r, c * 16 + l15)] = f2b(sA[c][r]);
        oA[c][r] *= alA[r];
      }
    }
    int prow = wv * 16 + l15;
    {
      short8 ap0 = *reinterpret_cast<const short8*>(&smem[PsO + vrot(prow, lg * 8)]);
      short8 ap1 = *reinterpret_cast<const short8*>(&smem[PsO + vrot(prow, 32 + lg * 8)]);
      #pragma unroll
      for (int c = 0; c < 4; ++c)
        oA[c] = mfma16(ap1, vb1[c], mfma16(ap0, vb0[c], oA[c]));
    }
    // ---- PV B (same Ps rows reused; same-wave ordering) ----
    if (doB) {
      #pragma unroll
      for (int c = 0; c < 4; ++c) {
        #pragma unroll
        for (int r = 0; r < 4; ++r) {
          smem[PsO + vrot(wv * 16 + lg * 4 + r, c * 16 + l15)] = f2b(sB[c][r]);
          oB[c][r] *= alB[r];
        }
      }
      short8 bp0 = *reinterpret_cast<const short8*>(&smem[PsO + vrot(prow, lg * 8)]);
      short8 bp1 = *reinterpret_cast<const short8*>(&smem[PsO + vrot(prow, 32 + lg * 8)]);
      #pragma unroll
      for (int c = 0; c < 4; ++c)
        oB[c] = mfma16(bp1, vb1[c], mfma16(bp0, vb0[c], oB[c]));
    }
    // ---- write prefetched tile into the other buffer ----
    if (kt + 2 <= qtA) {
      *reinterpret_cast<short8*>(&smem[ksn + kslot0]) = nk0;
      *reinterpret_cast<short8*>(&smem[ksn + kslot1]) = nk1;
      #pragma unroll
      for (int j = 0; j < 8; ++j) smem[vtn + vslot[j]] = (u16)nv0[j];
      #pragma unroll
      for (int j = 0; j < 8; ++j) smem[vtn + vslot[8 + j]] = (u16)nv1[j];
    }
    __syncthreads(); // single barrier per tile
    cur ^= 1;
  }
  // ---- write partials (own slot; no inter-block communication) ----
  size_t pbA = ((((size_t)(b * NH + h)) * 32 + qtA) * 2 + sp) * 4224;
  size_t pbB = ((((size_t)(b * NH + h)) * 32 + qtB) * 2 + sp) * 4224;
  #pragma unroll
  for (int c = 0; c < 4; ++c) {
    #pragma unroll
    for (int r = 0; r < 4; ++r) {
      int row = wv * 16 + lg * 4 + r;
      part[pbA + row * 64 + c * 16 + l15] = oA[c][r];
      part[pbB + row * 64 + c * 16 + l15] = oB[c][r];
    }
  }
  if (l15 == 0) {
    #pragma unroll
    for (int r = 0; r < 4; ++r) {
      int row = wv * 16 + lg * 4 + r;
      part[pbA + 4096 + row] = mA[r];
      part[pbA + 4160 + row] = lA[r];
      part[pbB + 4096 + row] = mB[r];
      part[pbB + 4160 + row] = lB[r];
    }
  }
}

// ---------------- 2-way flash merge of split-K partials -> ATT (bf16) ----------------
__global__ __launch_bounds__(256) void attn_merge(const float* __restrict__ part,
    u16* __restrict__ ATT) {
  int qt = blockIdx.x, h = blockIdx.y, b = blockIdx.z;
  int t = threadIdx.x;
  int row = t >> 2, c0 = (t & 3) * 16;
  size_t p0 = ((((size_t)(b * NH + h)) * 32 + qt) * 2) * 4224;
  size_t p1 = p0 + 4224;
  float m0 = part[p0 + 4096 + row], l0 = part[p0 + 4160 + row];
  float m1 = part[p1 + 4096 + row], l1 = part[p1 + 4160 + row];
  float mm = fmaxf(m0, m1);
  float a0 = __expf(m0 - mm), a1 = __expf(m1 - mm);
  float li = 1.0f / (l0 * a0 + l1 * a1);
  size_t ob = (size_t)(b * SEQ + qt * 64 + row) * HID + h * HD + c0;
  #pragma unroll
  for (int j4 = 0; j4 < 4; ++j4) {
    float4 v0 = *reinterpret_cast<const float4*>(&part[p0 + row * 64 + c0 + j4 * 4]);
    float4 v1 = *reinterpret_cast<const float4*>(&part[p1 + row * 64 + c0 + j4 * 4]);
    ushort4 o4;
    o4.x = f2b((v0.x * a0 + v1.x * a1) * li);
    o4.y = f2b((v0.y * a0 + v1.y * a1) * li);
    o4.z = f2b((v0.z * a0 + v1.z * a1) * li);
    o4.w = f2b((v0.w * a0 + v1.w * a1) * li);
    *reinterpret_cast<ushort4*>(&ATT[ob + j4 * 4]) = o4;
  }
}

extern "C" void kernel_launch(void* const* d_in, const int* in_sizes, int n_in,
                              void* d_out, int out_size, void* d_ws, size_t ws_size,
                              hipStream_t stream) {
  const float* x      = (const float*)d_in[0];
  const float* Wq     = (const float*)d_in[1];
  const float* bq     = (const float*)d_in[2];
  const float* Wk     = (const float*)d_in[3];
  const float* bk     = (const float*)d_in[4];
  const float* Wv     = (const float*)d_in[5];
  const float* bv     = (const float*)d_in[6];
  const float* Wo     = (const float*)d_in[7];
  const float* bo     = (const float*)d_in[8];
  const float* relpos = (const float*)d_in[9];
  const float* gamma  = (const float*)d_in[10];
  const float* beta   = (const float*)d_in[11];
  const float* Wrk    = (const float*)d_in[12];
  const float* brk    = (const float*)d_in[13];
  const float* Wrq    = (const float*)d_in[14];
  const float* brq    = (const float*)d_in[15];
  float* out = (float*)d_out;

  u16* wsu = (u16*)d_ws;
  size_t off = 0;
  auto alloc = [&](size_t n) { u16* p = wsu + off; off += n; return p; };
  u16* xb   = alloc(4194304);
  u16* Eb   = alloc(524288);
  u16* WtQ  = alloc(1048576);  // contiguous: WtQ|WtK|WtV for merged QKV GEMM
  u16* WtK  = alloc(1048576);
  u16* WtV  = alloc(1048576);
  u16* WtO  = alloc(1048576);
  u16* WtRK = alloc(1048576);  // contiguous: WtRK|WtRQ for merged rel GEMM
  u16* WtRQ = alloc(1048576);
  u16* Qb2  = alloc(4194304);
  u16* Kb2  = alloc(4194304);
  u16* Vb2  = alloc(4194304);
  u16* ATTb = alloc(4194304);
  u16* RKb2 = alloc(524288);
  u16* RQb2 = alloc(524288);
  float* qrk0 = (float*)(wsu + off); off += 131072;
  float* krq0 = (float*)(wsu + off); off += 131072;
  u16* bandT = alloc((size_t)NB * NH * 32 * 9 * 4096); // 75.5 MB tile-layout bias
  float* part = (float*)(wsu + off); off += (size_t)NB * NH * 32 * 2 * 4224 * 2; // 34.6 MB f32 partials

  ln_kernel<<<512, 256, 0, stream>>>(relpos, gamma, beta, Eb);
  conv_bf16<<<2048, 256, 0, stream>>>(x, xb, 4194304);
  P6 p6;
  p6.s[0] = Wq; p6.s[1] = Wk; p6.s[2] = Wv; p6.s[3] = Wo; p6.s[4] = Wrk; p6.s[5] = Wrq;
  p6.d[0] = WtQ; p6.d[1] = WtK; p6.d[2] = WtV; p6.d[3] = WtO; p6.d[4] = WtRK; p6.d[5] = WtRQ;
  dim3 gT(32, 32, 6);
  transp_all<<<gT, 256, 0, stream>>>(p6);

  GO goQKV = {{bq, bk, bv}, {Qb2, Kb2, Vb2}};
  dim3 gQKV(24, 32); // 768 blocks -> 3 blocks/CU
  gemm_bf16<false><<<gQKV, 512, 0, stream>>>(xb, WtQ, goQKV);
  GO goRel = {{brk, brq, brq}, {RKb2, RQb2, RQb2}};
  dim3 gRel2(16, 4);
  gemm_bf16<false><<<gRel2, 512, 0, stream>>>(Eb, WtRK, goRel);

  biasqk<<<1024, 256, 0, stream>>>(Qb2, Kb2, RKb2, RQb2, qrk0, krq0);

  dim3 gB(32, NH, NB);
  bias_kernel<<<gB, 256, 0, stream>>>(Qb2, Kb2, RKb2, RQb2, bandT);

  dim3 gA(32, NH, NB); // pair x parity: 1024 uniform blocks
  attn_mfma<<<gA, 256, 0, stream>>>(Qb2, Kb2, Vb2, qrk0, krq0, bandT, part);
  attn_merge<<<gB, 256, 0, stream>>>(part, ATTb);

  GO goOut = {{bo, bo, bo}, {out, out, out}};
  dim3 gBig(8, 32);
  gemm_bf16<true><<<gBig, 512, 0, stream>>>(ATTb, WtO, goOut);
}

// Round 13
// 219.928 us; speedup vs baseline: 1.0435x; 1.0435x over previous
//
#include <hip/hip_runtime.h>
#include <math.h>

#define NH 16
#define HD 64
#define HID 1024
#define SEQ 2048
#define NB 2

typedef __attribute__((ext_vector_type(8))) short short8;
typedef __attribute__((ext_vector_type(4))) float f32x4;
typedef unsigned short u16;
typedef unsigned int u32;

constexpr float LN_EPS_C = 1e-5f;
constexpr float SM_SCALE = 0.07216878364870323f; // 1/sqrt(64*3)

__device__ inline u16 f2b(float f) {
  unsigned u = __builtin_bit_cast(unsigned, f);
  u = (u + 0x7FFFu + ((u >> 16) & 1u)) >> 16;
  return (u16)u;
}
__device__ inline float b2f(u16 h) {
  unsigned u = ((unsigned)h) << 16;
  return __builtin_bit_cast(float, u);
}
__device__ inline u32 pk2(float lo, float hi) {
  return (u32)f2b(lo) | ((u32)f2b(hi) << 16);
}
__device__ inline f32x4 mfma16(short8 a, short8 b, f32x4 c) {
  return __builtin_amdgcn_mfma_f32_16x16x32_bf16(a, b, c, 0, 0, 0);
}
// swizzled read of a [rows][64] bf16 tile whose writes used slot = chunk^(row&7)
__device__ inline short8 swz8(const u16* base, int row, int hc) {
  return *reinterpret_cast<const short8*>(&base[row * 64 + 8 * (hc ^ (row & 7))]);
}
// add-rotate swizzle for [64 row][72-stride] tiles, col in [0,64).
__device__ inline int vrot(int row, int col) {
  return row * 72 + ((col + 16 * ((row >> 3) & 3)) & 63);
}
// DPP row-rotate reduction within the 16-lane row group
template <int N>
__device__ inline float rorf(float x) {
  return __builtin_bit_cast(float,
      __builtin_amdgcn_update_dpp(0, __builtin_bit_cast(int, x),
                                  0x120 + N, 0xF, 0xF, true));
}
__device__ inline float rmax16(float x) {
  x = fmaxf(x, rorf<1>(x)); x = fmaxf(x, rorf<2>(x));
  x = fmaxf(x, rorf<4>(x)); x = fmaxf(x, rorf<8>(x));
  return x;
}
__device__ inline float rsum16(float x) {
  x += rorf<1>(x); x += rorf<2>(x); x += rorf<4>(x); x += rorf<8>(x);
  return x;
}

// ---------------- LayerNorm over relpos_table rows -> bf16 ----------------
__global__ __launch_bounds__(256) void ln_kernel(const float* __restrict__ tbl,
    const float* __restrict__ gamma, const float* __restrict__ beta,
    u16* __restrict__ e) {
  int row = blockIdx.x;
  int t = threadIdx.x;
  const float4* rp = reinterpret_cast<const float4*>(tbl + (size_t)row * HID);
  float4 x = rp[t];
  float s = x.x + x.y + x.z + x.w;
  float ss = x.x * x.x + x.y * x.y + x.z * x.z + x.w * x.w;
  #pragma unroll
  for (int o = 1; o < 64; o <<= 1) {
    s += __shfl_xor(s, o);
    ss += __shfl_xor(ss, o);
  }
  __shared__ float sb[4], ssb[4];
  int w = t >> 6;
  if ((t & 63) == 0) { sb[w] = s; ssb[w] = ss; }
  __syncthreads();
  s = sb[0] + sb[1] + sb[2] + sb[3];
  ss = ssb[0] + ssb[1] + ssb[2] + ssb[3];
  float mu = s * (1.0f / HID);
  float var = ss * (1.0f / HID) - mu * mu;
  float rs = rsqrtf(var + LN_EPS_C);
  float4 g = reinterpret_cast<const float4*>(gamma)[t];
  float4 bt = reinterpret_cast<const float4*>(beta)[t];
  ushort4 o4;
  o4.x = f2b((x.x - mu) * rs * g.x + bt.x);
  o4.y = f2b((x.y - mu) * rs * g.y + bt.y);
  o4.z = f2b((x.z - mu) * rs * g.z + bt.z);
  o4.w = f2b((x.w - mu) * rs * g.w + bt.w);
  *reinterpret_cast<ushort4*>(&e[(size_t)row * HID + t * 4]) = o4;
}

// ---------------- f32 -> bf16 convert ----------------
__global__ __launch_bounds__(256) void conv_bf16(const float* __restrict__ src,
    u16* __restrict__ dst, int n) {
  int i = (blockIdx.x * 256 + threadIdx.x) * 8;
  if (i >= n) return;
  float4 a = *reinterpret_cast<const float4*>(&src[i]);
  float4 c = *reinterpret_cast<const float4*>(&src[i + 4]);
  short8 o;
  o[0] = (short)f2b(a.x); o[1] = (short)f2b(a.y); o[2] = (short)f2b(a.z); o[3] = (short)f2b(a.w);
  o[4] = (short)f2b(c.x); o[5] = (short)f2b(c.y); o[6] = (short)f2b(c.z); o[7] = (short)f2b(c.w);
  *reinterpret_cast<short8*>(&dst[i]) = o;
}

// ---------------- all 6 weight transposes in one launch ----------------
struct P6 {
  const float* s[6];
  u16* d[6];
};
__global__ __launch_bounds__(256) void transp_all(P6 p) {
  __shared__ float T[32][33];
  const float* W = p.s[blockIdx.z];
  u16* Wt = p.d[blockIdx.z];
  int bn = blockIdx.x * 32, bk = blockIdx.y * 32;
  int t = threadIdx.x;
  int r = t >> 3, c4 = (t & 7) * 4;
  float4 v = *reinterpret_cast<const float4*>(&W[(size_t)(bk + r) * HID + bn + c4]);
  T[r][c4 + 0] = v.x; T[r][c4 + 1] = v.y; T[r][c4 + 2] = v.z; T[r][c4 + 3] = v.w;
  __syncthreads();
  int n = t >> 3, k4 = (t & 7) * 4;
  ushort4 o;
  o.x = f2b(T[k4 + 0][n]); o.y = f2b(T[k4 + 1][n]);
  o.z = f2b(T[k4 + 2][n]); o.w = f2b(T[k4 + 3][n]);
  *reinterpret_cast<ushort4*>(&Wt[(size_t)(bn + n) * HID + bk + k4]) = o;
}

// ---------------- bf16 MFMA GEMM: 512 threads, 128x128, BK=64, XCD swizzle ----------------
struct GO {
  const float* bias[3];
  void* out[3];
};
template <bool F32OUT>
__global__ __launch_bounds__(512) void gemm_bf16(const u16* __restrict__ A,
    const u16* __restrict__ Bt, GO go) {
  __shared__ u16 Al[8192]; // [128][64] swizzled
  __shared__ u16 Bl[8192];
  int t = threadIdx.x;
  int gx = gridDim.x;
  int nwg = gx * gridDim.y;
  int lin = blockIdx.y * gx + blockIdx.x;
  lin = (lin & 7) * (nwg >> 3) + (lin >> 3); // bijective (nwg % 8 == 0)
  int cb = (lin % gx) * 128, rb = (lin / gx) * 128;
  int which = cb >> 10, cbl = cb & 1023;
  const float* bias = go.bias[which];
  void* Cout = go.out[which];
  int wv = t >> 6, lane = t & 63, l15 = lane & 15, lg = lane >> 4;
  int wr = (wv >> 2) * 64, wc = (wv & 3) * 32;
  int srow = t >> 2, sch = t & 3;
  f32x4 acc[4][2];
  #pragma unroll
  for (int i = 0; i < 4; ++i)
    #pragma unroll
    for (int j = 0; j < 2; ++j) acc[i][j] = (f32x4){0.f, 0.f, 0.f, 0.f};
  const u16* Ap = A + (size_t)(rb + srow) * HID;
  const u16* Bp = Bt + (size_t)(cb + srow) * HID;
  int slot0 = 8 * (sch ^ (srow & 7));
  int slot1 = 8 * ((sch + 4) ^ (srow & 7));
  short8 pa0 = *reinterpret_cast<const short8*>(&Ap[sch * 8]);
  short8 pa1 = *reinterpret_cast<const short8*>(&Ap[(sch + 4) * 8]);
  short8 pb0 = *reinterpret_cast<const short8*>(&Bp[sch * 8]);
  short8 pb1 = *reinterpret_cast<const short8*>(&Bp[(sch + 4) * 8]);
  for (int kk = 0; kk < HID; kk += 64) {
    __syncthreads();
    *reinterpret_cast<short8*>(&Al[srow * 64 + slot0]) = pa0;
    *reinterpret_cast<short8*>(&Al[srow * 64 + slot1]) = pa1;
    *reinterpret_cast<short8*>(&Bl[srow * 64 + slot0]) = pb0;
    *reinterpret_cast<short8*>(&Bl[srow * 64 + slot1]) = pb1;
    __syncthreads();
    if (kk + 64 < HID) {
      pa0 = *reinterpret_cast<const short8*>(&Ap[kk + 64 + sch * 8]);
      pa1 = *reinterpret_cast<const short8*>(&Ap[kk + 64 + (sch + 4) * 8]);
      pb0 = *reinterpret_cast<const short8*>(&Bp[kk + 64 + sch * 8]);
      pb1 = *reinterpret_cast<const short8*>(&Bp[kk + 64 + (sch + 4) * 8]);
    }
    #pragma unroll
    for (int s = 0; s < 2; ++s) {
      short8 am[4], bn[2];
      #pragma unroll
      for (int i = 0; i < 4; ++i) am[i] = swz8(Al, wr + i * 16 + l15, s * 4 + lg);
      #pragma unroll
      for (int j = 0; j < 2; ++j) bn[j] = swz8(Bl, wc + j * 16 + l15, s * 4 + lg);
      #pragma unroll
      for (int i = 0; i < 4; ++i)
        #pragma unroll
        for (int j = 0; j < 2; ++j)
          acc[i][j] = mfma16(am[i], bn[j], acc[i][j]);
    }
  }
  #pragma unroll
  for (int j = 0; j < 2; ++j) {
    float bv = bias[cbl + wc + j * 16 + l15];
    #pragma unroll
    for (int i = 0; i < 4; ++i) {
      #pragma unroll
      for (int r = 0; r < 4; ++r) {
        size_t idx = (size_t)(rb + wr + i * 16 + lg * 4 + r) * HID + cbl + wc + j * 16 + l15;
        float v = acc[i][j][r] + bv;
        if (F32OUT) reinterpret_cast<float*>(Cout)[idx] = v;
        else reinterpret_cast<u16*>(Cout)[idx] = f2b(v);
      }
    }
  }
}

// ---------------- bf16 MFMA GEMM: 256 threads, 64x128 tile (2+ blocks/CU), XCD swizzle ----------------
template <bool F32OUT>
__global__ __launch_bounds__(256) void gemm_m64(const u16* __restrict__ A,
    const u16* __restrict__ Bt, GO go) {
  __shared__ u16 Al[4096]; // [64][64] swizzled
  __shared__ u16 Bl[8192]; // [128][64] swizzled
  int t = threadIdx.x;
  int gx = gridDim.x;
  int nwg = gx * gridDim.y;
  int lin = blockIdx.y * gx + blockIdx.x;
  lin = (lin & 7) * (nwg >> 3) + (lin >> 3); // bijective (nwg % 8 == 0)
  int cb = (lin % gx) * 128, rb = (lin / gx) * 64;
  int which = cb >> 10, cbl = cb & 1023;
  const float* bias = go.bias[which];
  void* Cout = go.out[which];
  int wv = t >> 6, lane = t & 63, l15 = lane & 15, lg = lane >> 4;
  int wc = wv * 32;
  // A staging: 64 rows x 8 chunks, 2/thread
  int arow = t >> 2, ach = t & 3;
  int aslot0 = 8 * (ach ^ (arow & 7));
  int aslot1 = 8 * ((ach + 4) ^ (arow & 7));
  // B staging: 128 rows x 8 chunks, 4/thread
  int brow = t >> 1, bch = (t & 1) * 4;
  const u16* Ap = A + (size_t)(rb + arow) * HID;
  const u16* Bp = Bt + (size_t)(cb + brow) * HID;
  f32x4 acc[4][2];
  #pragma unroll
  for (int i = 0; i < 4; ++i)
    #pragma unroll
    for (int j = 0; j < 2; ++j) acc[i][j] = (f32x4){0.f, 0.f, 0.f, 0.f};
  short8 pa0 = *reinterpret_cast<const short8*>(&Ap[ach * 8]);
  short8 pa1 = *reinterpret_cast<const short8*>(&Ap[(ach + 4) * 8]);
  short8 pb[4];
  #pragma unroll
  for (int j = 0; j < 4; ++j)
    pb[j] = *reinterpret_cast<const short8*>(&Bp[(bch + j) * 8]);
  for (int kk = 0; kk < HID; kk += 64) {
    __syncthreads();
    *reinterpret_cast<short8*>(&Al[arow * 64 + aslot0]) = pa0;
    *reinterpret_cast<short8*>(&Al[arow * 64 + aslot1]) = pa1;
    #pragma unroll
    for (int j = 0; j < 4; ++j)
      *reinterpret_cast<short8*>(&Bl[brow * 64 + 8 * ((bch + j) ^ (brow & 7))]) = pb[j];
    __syncthreads();
    if (kk + 64 < HID) {
      pa0 = *reinterpret_cast<const short8*>(&Ap[kk + 64 + ach * 8]);
      pa1 = *reinterpret_cast<const short8*>(&Ap[kk + 64 + (ach + 4) * 8]);
      #pragma unroll
      for (int j = 0; j < 4; ++j)
        pb[j] = *reinterpret_cast<const short8*>(&Bp[kk + 64 + (bch + j) * 8]);
    }
    #pragma unroll
    for (int s = 0; s < 2; ++s) {
      short8 am[4], bn[2];
      #pragma unroll
      for (int i = 0; i < 4; ++i) am[i] = swz8(Al, i * 16 + l15, s * 4 + lg);
      #pragma unroll
      for (int j = 0; j < 2; ++j) bn[j] = swz8(Bl, wc + j * 16 + l15, s * 4 + lg);
      #pragma unroll
      for (int i = 0; i < 4; ++i)
        #pragma unroll
        for (int j = 0; j < 2; ++j)
          acc[i][j] = mfma16(am[i], bn[j], acc[i][j]);
    }
  }
  #pragma unroll
  for (int j = 0; j < 2; ++j) {
    float bv = bias[cbl + wc + j * 16 + l15];
    #pragma unroll
    for (int i = 0; i < 4; ++i) {
      #pragma unroll
      for (int r = 0; r < 4; ++r) {
        size_t idx = (size_t)(rb + i * 16 + lg * 4 + r) * HID + cbl + wc + j * 16 + l15;
        float v = acc[i][j][r] + bv;
        if (F32OUT) reinterpret_cast<float*>(Cout)[idx] = v;
        else reinterpret_cast<u16*>(Cout)[idx] = f2b(v);
      }
    }
  }
}

// ---------------- rank-1 bias precompute (PRESCALED) ----------------
__global__ __launch_bounds__(256) void biasqk(const u16* __restrict__ Qb,
    const u16* __restrict__ Kb, const u16* __restrict__ RKb,
    const u16* __restrict__ RQb, float* __restrict__ qrk0,
    float* __restrict__ krq0) {
  int o = blockIdx.x * 64 + (threadIdx.x >> 2);
  int sub = threadIdx.x & 3;
  int b = o >> 15, h = (o >> 11) & 15, i = o & 2047;
  size_t rbase = (size_t)(b * SEQ + i) * HID + h * HD + sub * 16;
  size_t tbase = (size_t)h * HD + sub * 16;
  float s1 = 0.f, s2 = 0.f;
  #pragma unroll
  for (int c = 0; c < 2; ++c) {
    short8 qv = *reinterpret_cast<const short8*>(&Qb[rbase + c * 8]);
    short8 rv = *reinterpret_cast<const short8*>(&RKb[tbase + c * 8]);
    short8 kv = *reinterpret_cast<const short8*>(&Kb[rbase + c * 8]);
    short8 uv = *reinterpret_cast<const short8*>(&RQb[tbase + c * 8]);
    #pragma unroll
    for (int j = 0; j < 8; ++j) {
      s1 += b2f((u16)qv[j]) * b2f((u16)rv[j]);
      s2 += b2f((u16)kv[j]) * b2f((u16)uv[j]);
    }
  }
  s1 += __shfl_xor(s1, 1); s1 += __shfl_xor(s1, 2);
  s2 += __shfl_xor(s2, 1); s2 += __shfl_xor(s2, 2);
  if (sub == 0) { qrk0[o] = s1 * SM_SCALE; krq0[o] = s2 * SM_SCALE; }
}

// ---------------- band bias precompute -> per-tile thread-ordered layout (PRESCALED) ----------------
__global__ __launch_bounds__(256, 3) void bias_kernel(
    const u16* __restrict__ Qb, const u16* __restrict__ Kb,
    const u16* __restrict__ RKb, const u16* __restrict__ RQb,
    u16* __restrict__ bandT) {
  __shared__ u16 smem[20992]; // 41984 B -> 3 blocks/CU
  const int KsO = 0, UO = 4096;
  const int RKO = UO, RQO = UO + 8192;
  const int G1O = UO, G2O = UO + 8448;

  int qt = blockIdx.x;
  int h = blockIdx.y, b = blockIdx.z;
  int q0 = qt * 64;
  int t = threadIdx.x;
  int wv = t >> 6, lane = t & 63, l15 = lane & 15, lg = lane >> 4;
  int qs = q0 + wv * 16;
  int hoff = h * HD;

  size_t qgrow = (size_t)(b * SEQ + qs + l15) * HID + hoff;
  short8 aq0 = *reinterpret_cast<const short8*>(&Qb[qgrow + lg * 8]);
  short8 aq1 = *reinterpret_cast<const short8*>(&Qb[qgrow + 32 + lg * 8]);

  const f32x4 Z = (f32x4){0.f, 0.f, 0.f, 0.f};
  int vr = t >> 2, vc8 = (t & 3) * 8;
  int ktlo = qt - 8; if (ktlo < 0) ktlo = 0;
  size_t tbase = (((size_t)(b * NH + h) * 32 + qt) * 9) << 12;

  for (int kt = ktlo; kt <= qt; ++kt) {
    int k0 = kt * 64;
    int dt = qt - kt;
    int wlo = 448 - 64 * dt; if (wlo < 0) wlo = 0;
    __syncthreads(); // #1: previous iteration's gathers done
    {
      const u16* kg = &Kb[(size_t)(b * SEQ + k0 + vr) * HID + hoff];
      int c0 = vc8 >> 3;
      *reinterpret_cast<short8*>(&smem[KsO + vr * 64 + 8 * (c0 ^ (vr & 7))]) =
          *reinterpret_cast<const short8*>(&kg[vc8]);
      *reinterpret_cast<short8*>(&smem[KsO + vr * 64 + 8 * ((c0 + 4) ^ (vr & 7))]) =
          *reinterpret_cast<const short8*>(&kg[vc8 + 32]);
    }
    for (int e2 = t; e2 < 1024; e2 += 256) {
      int rr = e2 >> 3, cch = e2 & 7;
      int wr2 = wlo + rr; if (wr2 > 511) wr2 = 511;
      size_t gb = (size_t)wr2 * HID + hoff + cch * 8;
      int slot = 8 * (cch ^ (rr & 7));
      *reinterpret_cast<short8*>(&smem[RKO + rr * 64 + slot]) =
          *reinterpret_cast<const short8*>(&RKb[gb]);
      *reinterpret_cast<short8*>(&smem[RQO + rr * 64 + slot]) =
          *reinterpret_cast<const short8*>(&RQb[gb]);
    }
    __syncthreads(); // #2: staging visible
    u32 g1p[16], g2p[16];
    #pragma unroll
    for (int cw = 0; cw < 8; ++cw) {
      short8 r0 = swz8(&smem[RKO], cw * 16 + l15, lg);
      short8 r1 = swz8(&smem[RKO], cw * 16 + l15, 4 + lg);
      f32x4 g = mfma16(r1, aq1, mfma16(r0, aq0, Z));
      g1p[2 * cw] = pk2(g[0], g[1]);
      g1p[2 * cw + 1] = pk2(g[2], g[3]);
    }
    short8 kw0 = swz8(&smem[KsO], wv * 16 + l15, lg);
    short8 kw1 = swz8(&smem[KsO], wv * 16 + l15, 4 + lg);
    #pragma unroll
    for (int cw = 0; cw < 8; ++cw) {
      short8 u0 = swz8(&smem[RQO], cw * 16 + l15, lg);
      short8 u1 = swz8(&smem[RQO], cw * 16 + l15, 4 + lg);
      f32x4 g = mfma16(u1, kw1, mfma16(u0, kw0, Z));
      g2p[2 * cw] = pk2(g[0], g[1]);
      g2p[2 * cw + 1] = pk2(g[2], g[3]);
    }
    __syncthreads(); // #3: band reads done; U reusable for G
    #pragma unroll
    for (int cw = 0; cw < 8; ++cw) {
      *reinterpret_cast<uint2*>(&smem[G1O + (wv * 16 + l15) * 132 + cw * 16 + lg * 4]) =
          make_uint2(g1p[2 * cw], g1p[2 * cw + 1]);
      *reinterpret_cast<uint2*>(&smem[G2O + (wv * 16 + l15) * 132 + cw * 16 + lg * 4]) =
          make_uint2(g2p[2 * cw], g2p[2 * cw + 1]);
    }
    __syncthreads(); // #4: G visible
    u16* outp = bandT + tbase + ((size_t)dt << 12) + t * 16;
    #pragma unroll
    for (int c = 0; c < 4; ++c) {
      float vv[4];
      #pragma unroll
      for (int r = 0; r < 4; ++r) {
        int q = qs + lg * 4 + r;
        int k = k0 + c * 16 + l15;
        int wi = 511 - (q - k) - wlo; if (wi < 0) wi = 0;
        vv[r] = (b2f(smem[G1O + (wv * 16 + lg * 4 + r) * 132 + wi]) +
                 b2f(smem[G2O + (c * 16 + l15) * 132 + wi])) * SM_SCALE;
      }
      *reinterpret_cast<uint2*>(outp + c * 4) =
          make_uint2(pk2(vv[0], vv[1]), pk2(vv[2], vv[3]));
    }
  }
}

// ---------------- fused DeBERTa flash attention: paired q-tiles (round-10 proven) ----------------
__global__ __launch_bounds__(256, 2) void attn_mfma(
    const u16* __restrict__ Qb, const u16* __restrict__ Kb,
    const u16* __restrict__ Vb, const float* __restrict__ qrk0,
    const float* __restrict__ krq0, const u16* __restrict__ bandT,
    u16* __restrict__ ATT) {
  __shared__ u16 smem[22016];
  const int KsB[2] = {0, 4096};
  const int VtB[2] = {8192, 12800};
  const int PsO = 17408;

  int qtA = 31 - (int)blockIdx.x; // heavy stream
  int qtB = (int)blockIdx.x;      // light stream (prefix of A's k-range)
  int h = blockIdx.y, b = blockIdx.z;
  int t = threadIdx.x;
  int wv = t >> 6, lane = t & 63, l15 = lane & 15, lg = lane >> 4;
  int hoff = h * HD;
  int bh = (b * NH + h) * SEQ;
  size_t tbaseA = (((size_t)(b * NH + h) * 32 + qtA) * 9) << 12;
  size_t tbaseB = (((size_t)(b * NH + h) * 32 + qtB) * 9) << 12;

  int qsA = qtA * 64 + wv * 16;
  int qsB = qtB * 64 + wv * 16;
  size_t qgA = (size_t)(b * SEQ + qsA + l15) * HID + hoff;
  size_t qgB = (size_t)(b * SEQ + qsB + l15) * HID + hoff;
  short8 aqA0 = *reinterpret_cast<const short8*>(&Qb[qgA + lg * 8]);
  short8 aqA1 = *reinterpret_cast<const short8*>(&Qb[qgA + 32 + lg * 8]);
  short8 aqB0 = *reinterpret_cast<const short8*>(&Qb[qgB + lg * 8]);
  short8 aqB1 = *reinterpret_cast<const short8*>(&Qb[qgB + 32 + lg * 8]);
  float qb0A[4], qb0B[4];
  #pragma unroll
  for (int r = 0; r < 4; ++r) {
    qb0A[r] = qrk0[bh + qsA + lg * 4 + r];
    qb0B[r] = qrk0[bh + qsB + lg * 4 + r];
  }

  float mA[4], lA[4], mB[4], lB[4];
  f32x4 oA[4], oB[4];
  #pragma unroll
  for (int r = 0; r < 4; ++r) { mA[r] = -INFINITY; lA[r] = 0.f; mB[r] = -INFINITY; lB[r] = 0.f; }
  #pragma unroll
  for (int c = 0; c < 4; ++c) {
    oA[c] = (f32x4){0.f, 0.f, 0.f, 0.f};
    oB[c] = (f32x4){0.f, 0.f, 0.f, 0.f};
  }

  const f32x4 Z = (f32x4){0.f, 0.f, 0.f, 0.f};
  int vr = t >> 2, vc8 = (t & 3) * 8;
  int c0s = vc8 >> 3;
  int kslot0 = vr * 64 + 8 * (c0s ^ (vr & 7));
  int kslot1 = vr * 64 + 8 * ((c0s + 4) ^ (vr & 7));
  int vslot[16];
  #pragma unroll
  for (int j = 0; j < 8; ++j) {
    vslot[j] = vrot(vc8 + j, vr);
    vslot[8 + j] = vrot(vc8 + 32 + j, vr);
  }

  // ---- prologue: stage tile 0 into buffer 0 ----
  {
    const u16* kg = &Kb[(size_t)(b * SEQ + vr) * HID + hoff];
    short8 k0v = *reinterpret_cast<const short8*>(&kg[vc8]);
    short8 k1v = *reinterpret_cast<const short8*>(&kg[vc8 + 32]);
    *reinterpret_cast<short8*>(&smem[KsB[0] + kslot0]) = k0v;
    *reinterpret_cast<short8*>(&smem[KsB[0] + kslot1]) = k1v;
    const u16* vg = &Vb[(size_t)(b * SEQ + vr) * HID + hoff];
    short8 v0v = *reinterpret_cast<const short8*>(&vg[vc8]);
    short8 v1v = *reinterpret_cast<const short8*>(&vg[vc8 + 32]);
    #pragma unroll
    for (int j = 0; j < 8; ++j) smem[VtB[0] + vslot[j]] = (u16)v0v[j];
    #pragma unroll
    for (int j = 0; j < 8; ++j) smem[VtB[0] + vslot[8 + j]] = (u16)v1v[j];
  }
  __syncthreads();

  int cur = 0;
  for (int kt = 0; kt <= qtA; ++kt) {
    int k0 = kt * 64;
    int dtA = qtA - kt;
    bool doB = (kt <= qtB);
    int dtB = qtB - kt;
    bool bandedA = (dtA <= 8);
    bool bandedB = doB && (dtB <= 8);
    int ksb = KsB[cur], vtb = VtB[cur];
    int ksn = KsB[cur ^ 1], vtn = VtB[cur ^ 1];

    // ---- early loads: bias tiles (coalesced), kq when needed, next K/V prefetch ----
    short8 pA0, pA1, pB0, pB1;
    if (bandedA) {
      const u16* tb = bandT + tbaseA + ((size_t)dtA << 12) + t * 16;
      pA0 = *reinterpret_cast<const short8*>(tb);
      pA1 = *reinterpret_cast<const short8*>(tb + 8);
    }
    if (bandedB) {
      const u16* tb = bandT + tbaseB + ((size_t)dtB << 12) + t * 16;
      pB0 = *reinterpret_cast<const short8*>(tb);
      pB1 = *reinterpret_cast<const short8*>(tb + 8);
    }
    float kq[4];
    if (dtA > 8 || (doB && dtB > 8)) {
      #pragma unroll
      for (int c = 0; c < 4; ++c) kq[c] = krq0[bh + k0 + c * 16 + l15];
    }
    short8 nk0, nk1, nv0, nv1;
    if (kt < qtA) {
      const u16* kg = &Kb[(size_t)(b * SEQ + k0 + 64 + vr) * HID + hoff];
      nk0 = *reinterpret_cast<const short8*>(&kg[vc8]);
      nk1 = *reinterpret_cast<const short8*>(&kg[vc8 + 32]);
      const u16* vg = &Vb[(size_t)(b * SEQ + k0 + 64 + vr) * HID + hoff];
      nv0 = *reinterpret_cast<const short8*>(&vg[vc8]);
      nv1 = *reinterpret_cast<const short8*>(&vg[vc8 + 32]);
    }

    // ---- K fragments (shared by A and B) ----
    short8 kb0[4], kb1[4];
    #pragma unroll
    for (int c = 0; c < 4; ++c) {
      kb0[c] = swz8(&smem[ksb], c * 16 + l15, lg);
      kb1[c] = swz8(&smem[ksb], c * 16 + l15, 4 + lg);
    }
    f32x4 sA[4], sB[4];
    #pragma unroll
    for (int c = 0; c < 4; ++c)
      sA[c] = mfma16(aqA1, kb1[c], mfma16(aqA0, kb0[c], Z));
    if (doB) {
      #pragma unroll
      for (int c = 0; c < 4; ++c)
        sB[c] = mfma16(aqB1, kb1[c], mfma16(aqB0, kb0[c], Z));
    }
    // ---- bias (prescaled) + fma-scale + mask ----
    #pragma unroll
    for (int c = 0; c < 4; ++c) {
      #pragma unroll
      for (int r = 0; r < 4; ++r) {
        float bbv = bandedA ? b2f((u16)((c < 2 ? pA0 : pA1)[(c & 1) * 4 + r]))
                            : qb0A[r] + kq[c];
        float v = fmaf(sA[c][r], SM_SCALE, bbv);
        if (dtA == 0) {
          int ql = wv * 16 + lg * 4 + r, kl = c * 16 + l15;
          if (ql < kl) v = -INFINITY;
        }
        sA[c][r] = v;
      }
    }
    if (doB) {
      #pragma unroll
      for (int c = 0; c < 4; ++c) {
        #pragma unroll
        for (int r = 0; r < 4; ++r) {
          float bbv = bandedB ? b2f((u16)((c < 2 ? pB0 : pB1)[(c & 1) * 4 + r]))
                              : qb0B[r] + kq[c];
          float v = fmaf(sB[c][r], SM_SCALE, bbv);
          if (dtB == 0) {
            int ql = wv * 16 + lg * 4 + r, kl = c * 16 + l15;
            if (ql < kl) v = -INFINITY;
          }
          sB[c][r] = v;
        }
      }
    }
    // ---- softmax (DPP row reductions; two independent chains) ----
    float alA[4], alB[4];
    #pragma unroll
    for (int r = 0; r < 4; ++r) {
      float mx = fmaxf(fmaxf(sA[0][r], sA[1][r]), fmaxf(sA[2][r], sA[3][r]));
      mx = rmax16(mx);
      float mn = fmaxf(mA[r], mx);
      alA[r] = __expf(mA[r] - mn);
      float ps = 0.f;
      #pragma unroll
      for (int c = 0; c < 4; ++c) {
        float p = __expf(sA[c][r] - mn);
        sA[c][r] = p;
        ps += p;
      }
      ps = rsum16(ps);
      lA[r] = lA[r] * alA[r] + ps;
      mA[r] = mn;
    }
    if (doB) {
      #pragma unroll
      for (int r = 0; r < 4; ++r) {
        float mx = fmaxf(fmaxf(sB[0][r], sB[1][r]), fmaxf(sB[2][r], sB[3][r]));
        mx = rmax16(mx);
        float mn = fmaxf(mB[r], mx);
        alB[r] = __expf(mB[r] - mn);
        float ps = 0.f;
        #pragma unroll
        for (int c = 0; c < 4; ++c) {
          float p = __expf(sB[c][r] - mn);
          sB[c][r] = p;
          ps += p;
        }
        ps = rsum16(ps);
        lB[r] = lB[r] * alB[r] + ps;
        mB[r] = mn;
      }
    }
    // ---- V fragments (shared) ----
    short8 vb0[4], vb1[4];
    #pragma unroll
    for (int c = 0; c < 4; ++c) {
      int n = c * 16 + l15;
      vb0[c] = *reinterpret_cast<const short8*>(&smem[vtb + vrot(n, lg * 8)]);
      vb1[c] = *reinterpret_cast<const short8*>(&smem[vtb + vrot(n, 32 + lg * 8)]);
    }
    // ---- PV A ----
    #pragma unroll
    for (int c = 0; c < 4; ++c) {
      #pragma unroll
      for (int r = 0; r < 4; ++r) {
        smem[PsO + vrot(wv * 16 + lg * 4 + r, c * 16 + l15)] = f2b(sA[c][r]);
        oA[c][r] *= alA[r];
      }
    }
    int prow = wv * 16 + l15;
    {
      short8 ap0 = *reinterpret_cast<const short8*>(&smem[PsO + vrot(prow, lg * 8)]);
      short8 ap1 = *reinterpret_cast<const short8*>(&smem[PsO + vrot(prow, 32 + lg * 8)]);
      #pragma unroll
      for (int c = 0; c < 4; ++c)
        oA[c] = mfma16(ap1, vb1[c], mfma16(ap0, vb0[c], oA[c]));
    }
    // ---- PV B (same Ps rows reused; same-wave ordering) ----
    if (doB) {
      #pragma unroll
      for (int c = 0; c < 4; ++c) {
        #pragma unroll
        for (int r = 0; r < 4; ++r) {
          smem[PsO + vrot(wv * 16 + lg * 4 + r, c * 16 + l15)] = f2b(sB[c][r]);
          oB[c][r] *= alB[r];
        }
      }
      short8 bp0 = *reinterpret_cast<const short8*>(&smem[PsO + vrot(prow, lg * 8)]);
      short8 bp1 = *reinterpret_cast<const short8*>(&smem[PsO + vrot(prow, 32 + lg * 8)]);
      #pragma unroll
      for (int c = 0; c < 4; ++c)
        oB[c] = mfma16(bp1, vb1[c], mfma16(bp0, vb0[c], oB[c]));
    }
    // ---- write prefetched tile into the other buffer ----
    if (kt < qtA) {
      *reinterpret_cast<short8*>(&smem[ksn + kslot0]) = nk0;
      *reinterpret_cast<short8*>(&smem[ksn + kslot1]) = nk1;
      #pragma unroll
      for (int j = 0; j < 8; ++j) smem[vtn + vslot[j]] = (u16)nv0[j];
      #pragma unroll
      for (int j = 0; j < 8; ++j) smem[vtn + vslot[8 + j]] = (u16)nv1[j];
    }
    __syncthreads(); // single barrier per tile
    cur ^= 1;
  }
  #pragma unroll
  for (int r = 0; r < 4; ++r) { lA[r] = 1.0f / lA[r]; lB[r] = 1.0f / lB[r]; }
  #pragma unroll
  for (int c = 0; c < 4; ++c) {
    #pragma unroll
    for (int r = 0; r < 4; ++r) {
      size_t obA = (size_t)(b * SEQ + qsA + lg * 4 + r) * HID + hoff + c * 16 + l15;
      ATT[obA] = f2b(oA[c][r] * lA[r]);
      size_t obB = (size_t)(b * SEQ + qsB + lg * 4 + r) * HID + hoff + c * 16 + l15;
      ATT[obB] = f2b(oB[c][r] * lB[r]);
    }
  }
}

extern "C" void kernel_launch(void* const* d_in, const int* in_sizes, int n_in,
                              void* d_out, int out_size, void* d_ws, size_t ws_size,
                              hipStream_t stream) {
  const float* x      = (const float*)d_in[0];
  const float* Wq     = (const float*)d_in[1];
  const float* bq     = (const float*)d_in[2];
  const float* Wk     = (const float*)d_in[3];
  const float* bk     = (const float*)d_in[4];
  const float* Wv     = (const float*)d_in[5];
  const float* bv     = (const float*)d_in[6];
  const float* Wo     = (const float*)d_in[7];
  const float* bo     = (const float*)d_in[8];
  const float* relpos = (const float*)d_in[9];
  const float* gamma  = (const float*)d_in[10];
  const float* beta   = (const float*)d_in[11];
  const float* Wrk    = (const float*)d_in[12];
  const float* brk    = (const float*)d_in[13];
  const float* Wrq    = (const float*)d_in[14];
  const float* brq    = (const float*)d_in[15];
  float* out = (float*)d_out;

  u16* wsu = (u16*)d_ws;
  size_t off = 0;
  auto alloc = [&](size_t n) { u16* p = wsu + off; off += n; return p; };
  u16* xb   = alloc(4194304);
  u16* Eb   = alloc(524288);
  u16* WtQ  = alloc(1048576);  // contiguous: WtQ|WtK|WtV for merged QKV GEMM
  u16* WtK  = alloc(1048576);
  u16* WtV  = alloc(1048576);
  u16* WtO  = alloc(1048576);
  u16* WtRK = alloc(1048576);  // contiguous: WtRK|WtRQ for merged rel GEMM
  u16* WtRQ = alloc(1048576);
  u16* Qb2  = alloc(4194304);
  u16* Kb2  = alloc(4194304);
  u16* Vb2  = alloc(4194304);
  u16* ATTb = alloc(4194304);
  u16* RKb2 = alloc(524288);
  u16* RQb2 = alloc(524288);
  float* qrk0 = (float*)(wsu + off); off += 131072;
  float* krq0 = (float*)(wsu + off); off += 131072;
  u16* bandT = alloc((size_t)NB * NH * 32 * 9 * 4096); // 75.5 MB tile-layout bias

  ln_kernel<<<512, 256, 0, stream>>>(relpos, gamma, beta, Eb);
  conv_bf16<<<2048, 256, 0, stream>>>(x, xb, 4194304);
  P6 p6;
  p6.s[0] = Wq; p6.s[1] = Wk; p6.s[2] = Wv; p6.s[3] = Wo; p6.s[4] = Wrk; p6.s[5] = Wrq;
  p6.d[0] = WtQ; p6.d[1] = WtK; p6.d[2] = WtV; p6.d[3] = WtO; p6.d[4] = WtRK; p6.d[5] = WtRQ;
  dim3 gT(32, 32, 6);
  transp_all<<<gT, 256, 0, stream>>>(p6);

  GO goQKV = {{bq, bk, bv}, {Qb2, Kb2, Vb2}};
  dim3 gQKV(24, 32); // 768 blocks (%8==0) -> 3 blocks/CU, XCD-chunked
  gemm_bf16<false><<<gQKV, 512, 0, stream>>>(xb, WtQ, goQKV);
  GO goRel = {{brk, brq, brq}, {RKb2, RQb2, RQb2}};
  dim3 gRel2(16, 8); // m64: 128 blocks (%8==0)
  gemm_m64<false><<<gRel2, 256, 0, stream>>>(Eb, WtRK, goRel);

  biasqk<<<1024, 256, 0, stream>>>(Qb2, Kb2, RKb2, RQb2, qrk0, krq0);

  dim3 gB(32, NH, NB);
  bias_kernel<<<gB, 256, 0, stream>>>(Qb2, Kb2, RKb2, RQb2, bandT);

  dim3 gA(16, NH, NB); // paired q-tiles: 512 balanced blocks
  attn_mfma<<<gA, 256, 0, stream>>>(Qb2, Kb2, Vb2, qrk0, krq0, bandT, ATTb);

  GO goOut = {{bo, bo, bo}, {out, out, out}};
  dim3 gOut(8, 64); // m64: 512 blocks (%8==0) -> 2 blocks/CU
  gemm_m64<true><<<gOut, 256, 0, stream>>>(ATTb, WtO, goOut);
}

// Round 14
// 215.289 us; speedup vs baseline: 1.0660x; 1.0215x over previous
//
#include <hip/hip_runtime.h>
#include <math.h>

#define NH 16
#define HD 64
#define HID 1024
#define SEQ 2048
#define NB 2

typedef __attribute__((ext_vector_type(8))) short short8;
typedef __attribute__((ext_vector_type(4))) float f32x4;
typedef unsigned short u16;
typedef unsigned int u32;

constexpr float LN_EPS_C = 1e-5f;
constexpr float SM_SCALE = 0.07216878364870323f; // 1/sqrt(64*3)

__device__ inline u16 f2b(float f) {
  unsigned u = __builtin_bit_cast(unsigned, f);
  u = (u + 0x7FFFu + ((u >> 16) & 1u)) >> 16;
  return (u16)u;
}
__device__ inline float b2f(u16 h) {
  unsigned u = ((unsigned)h) << 16;
  return __builtin_bit_cast(float, u);
}
__device__ inline u32 pk2(float lo, float hi) {
  return (u32)f2b(lo) | ((u32)f2b(hi) << 16);
}
__device__ inline f32x4 mfma16(short8 a, short8 b, f32x4 c) {
  return __builtin_amdgcn_mfma_f32_16x16x32_bf16(a, b, c, 0, 0, 0);
}
// swizzled read of a [rows][64] bf16 tile whose writes used slot = chunk^(row&7)
__device__ inline short8 swz8(const u16* base, int row, int hc) {
  return *reinterpret_cast<const short8*>(&base[row * 64 + 8 * (hc ^ (row & 7))]);
}
// add-rotate swizzle for [64 row][72-stride] tiles, col in [0,64).
__device__ inline int vrot(int row, int col) {
  return row * 72 + ((col + 16 * ((row >> 3) & 3)) & 63);
}
// DPP row-rotate reduction within the 16-lane row group
template <int N>
__device__ inline float rorf(float x) {
  return __builtin_bit_cast(float,
      __builtin_amdgcn_update_dpp(0, __builtin_bit_cast(int, x),
                                  0x120 + N, 0xF, 0xF, true));
}
__device__ inline float rmax16(float x) {
  x = fmaxf(x, rorf<1>(x)); x = fmaxf(x, rorf<2>(x));
  x = fmaxf(x, rorf<4>(x)); x = fmaxf(x, rorf<8>(x));
  return x;
}
__device__ inline float rsum16(float x) {
  x += rorf<1>(x); x += rorf<2>(x); x += rorf<4>(x); x += rorf<8>(x);
  return x;
}

// ---------------- fused preprocessing: ln | f32->bf16 conv | 6x weight transpose ----------------
struct PrepArgs {
  const float* tbl; const float* gamma; const float* beta; u16* e;
  const float* x; u16* xb;
  const float* ws[6]; u16* wd[6];
};
__global__ __launch_bounds__(256) void prep_kernel(PrepArgs p) {
  __shared__ float T[32][33];
  __shared__ float sb[4], ssb[4];
  int bid = blockIdx.x;
  int t = threadIdx.x;
  if (bid < 512) {
    // LayerNorm over relpos_table row -> bf16
    int row = bid;
    const float4* rp = reinterpret_cast<const float4*>(p.tbl + (size_t)row * HID);
    float4 x = rp[t];
    float s = x.x + x.y + x.z + x.w;
    float ss = x.x * x.x + x.y * x.y + x.z * x.z + x.w * x.w;
    #pragma unroll
    for (int o = 1; o < 64; o <<= 1) {
      s += __shfl_xor(s, o);
      ss += __shfl_xor(ss, o);
    }
    int w = t >> 6;
    if ((t & 63) == 0) { sb[w] = s; ssb[w] = ss; }
    __syncthreads();
    s = sb[0] + sb[1] + sb[2] + sb[3];
    ss = ssb[0] + ssb[1] + ssb[2] + ssb[3];
    float mu = s * (1.0f / HID);
    float var = ss * (1.0f / HID) - mu * mu;
    float rs = rsqrtf(var + LN_EPS_C);
    float4 g = reinterpret_cast<const float4*>(p.gamma)[t];
    float4 bt = reinterpret_cast<const float4*>(p.beta)[t];
    ushort4 o4;
    o4.x = f2b((x.x - mu) * rs * g.x + bt.x);
    o4.y = f2b((x.y - mu) * rs * g.y + bt.y);
    o4.z = f2b((x.z - mu) * rs * g.z + bt.z);
    o4.w = f2b((x.w - mu) * rs * g.w + bt.w);
    *reinterpret_cast<ushort4*>(&p.e[(size_t)row * HID + t * 4]) = o4;
  } else if (bid < 2560) {
    // x f32 -> bf16
    int i = ((bid - 512) * 256 + t) * 8;
    float4 a = *reinterpret_cast<const float4*>(&p.x[i]);
    float4 c = *reinterpret_cast<const float4*>(&p.x[i + 4]);
    short8 o;
    o[0] = (short)f2b(a.x); o[1] = (short)f2b(a.y); o[2] = (short)f2b(a.z); o[3] = (short)f2b(a.w);
    o[4] = (short)f2b(c.x); o[5] = (short)f2b(c.y); o[6] = (short)f2b(c.z); o[7] = (short)f2b(c.w);
    *reinterpret_cast<short8*>(&p.xb[i]) = o;
  } else {
    // W[k][n] f32 -> Wt[n][k] bf16
    int z = (bid - 2560) >> 10;
    int rem = (bid - 2560) & 1023;
    int bn = (rem & 31) * 32, bk = (rem >> 5) * 32;
    const float* W = p.ws[z];
    u16* Wt = p.wd[z];
    int r = t >> 3, c4 = (t & 7) * 4;
    float4 v = *reinterpret_cast<const float4*>(&W[(size_t)(bk + r) * HID + bn + c4]);
    T[r][c4 + 0] = v.x; T[r][c4 + 1] = v.y; T[r][c4 + 2] = v.z; T[r][c4 + 3] = v.w;
    __syncthreads();
    int n = t >> 3, k4 = (t & 7) * 4;
    ushort4 o;
    o.x = f2b(T[k4 + 0][n]); o.y = f2b(T[k4 + 1][n]);
    o.z = f2b(T[k4 + 2][n]); o.w = f2b(T[k4 + 3][n]);
    *reinterpret_cast<ushort4*>(&Wt[(size_t)(bn + n) * HID + bk + k4]) = o;
  }
}

// ---------------- bf16 MFMA GEMM: 512 threads, 128x128, BK=64, XCD swizzle ----------------
struct GO {
  const float* bias[3];
  void* out[3];
};
template <bool F32OUT>
__global__ __launch_bounds__(512) void gemm_bf16(const u16* __restrict__ A,
    const u16* __restrict__ Bt, GO go) {
  __shared__ u16 Al[8192]; // [128][64] swizzled
  __shared__ u16 Bl[8192];
  int t = threadIdx.x;
  int gx = gridDim.x;
  int nwg = gx * gridDim.y;
  int lin = blockIdx.y * gx + blockIdx.x;
  lin = (lin & 7) * (nwg >> 3) + (lin >> 3); // bijective (nwg % 8 == 0)
  int cb = (lin % gx) * 128, rb = (lin / gx) * 128;
  int which = cb >> 10, cbl = cb & 1023;
  const float* bias = go.bias[which];
  void* Cout = go.out[which];
  int wv = t >> 6, lane = t & 63, l15 = lane & 15, lg = lane >> 4;
  int wr = (wv >> 2) * 64, wc = (wv & 3) * 32;
  int srow = t >> 2, sch = t & 3;
  f32x4 acc[4][2];
  #pragma unroll
  for (int i = 0; i < 4; ++i)
    #pragma unroll
    for (int j = 0; j < 2; ++j) acc[i][j] = (f32x4){0.f, 0.f, 0.f, 0.f};
  const u16* Ap = A + (size_t)(rb + srow) * HID;
  const u16* Bp = Bt + (size_t)(cb + srow) * HID;
  int slot0 = 8 * (sch ^ (srow & 7));
  int slot1 = 8 * ((sch + 4) ^ (srow & 7));
  short8 pa0 = *reinterpret_cast<const short8*>(&Ap[sch * 8]);
  short8 pa1 = *reinterpret_cast<const short8*>(&Ap[(sch + 4) * 8]);
  short8 pb0 = *reinterpret_cast<const short8*>(&Bp[sch * 8]);
  short8 pb1 = *reinterpret_cast<const short8*>(&Bp[(sch + 4) * 8]);
  for (int kk = 0; kk < HID; kk += 64) {
    __syncthreads();
    *reinterpret_cast<short8*>(&Al[srow * 64 + slot0]) = pa0;
    *reinterpret_cast<short8*>(&Al[srow * 64 + slot1]) = pa1;
    *reinterpret_cast<short8*>(&Bl[srow * 64 + slot0]) = pb0;
    *reinterpret_cast<short8*>(&Bl[srow * 64 + slot1]) = pb1;
    __syncthreads();
    if (kk + 64 < HID) {
      pa0 = *reinterpret_cast<const short8*>(&Ap[kk + 64 + sch * 8]);
      pa1 = *reinterpret_cast<const short8*>(&Ap[kk + 64 + (sch + 4) * 8]);
      pb0 = *reinterpret_cast<const short8*>(&Bp[kk + 64 + sch * 8]);
      pb1 = *reinterpret_cast<const short8*>(&Bp[kk + 64 + (sch + 4) * 8]);
    }
    #pragma unroll
    for (int s = 0; s < 2; ++s) {
      short8 am[4], bn[2];
      #pragma unroll
      for (int i = 0; i < 4; ++i) am[i] = swz8(Al, wr + i * 16 + l15, s * 4 + lg);
      #pragma unroll
      for (int j = 0; j < 2; ++j) bn[j] = swz8(Bl, wc + j * 16 + l15, s * 4 + lg);
      #pragma unroll
      for (int i = 0; i < 4; ++i)
        #pragma unroll
        for (int j = 0; j < 2; ++j)
          acc[i][j] = mfma16(am[i], bn[j], acc[i][j]);
    }
  }
  #pragma unroll
  for (int j = 0; j < 2; ++j) {
    float bv = bias[cbl + wc + j * 16 + l15];
    #pragma unroll
    for (int i = 0; i < 4; ++i) {
      #pragma unroll
      for (int r = 0; r < 4; ++r) {
        size_t idx = (size_t)(rb + wr + i * 16 + lg * 4 + r) * HID + cbl + wc + j * 16 + l15;
        float v = acc[i][j][r] + bv;
        if (F32OUT) reinterpret_cast<float*>(Cout)[idx] = v;
        else reinterpret_cast<u16*>(Cout)[idx] = f2b(v);
      }
    }
  }
}

// ---------------- bf16 MFMA GEMM: 256 threads, 64x128 tile, XCD swizzle ----------------
template <bool F32OUT>
__global__ __launch_bounds__(256) void gemm_m64(const u16* __restrict__ A,
    const u16* __restrict__ Bt, GO go) {
  __shared__ u16 Al[4096]; // [64][64] swizzled
  __shared__ u16 Bl[8192]; // [128][64] swizzled
  int t = threadIdx.x;
  int gx = gridDim.x;
  int nwg = gx * gridDim.y;
  int lin = blockIdx.y * gx + blockIdx.x;
  lin = (lin & 7) * (nwg >> 3) + (lin >> 3); // bijective (nwg % 8 == 0)
  int cb = (lin % gx) * 128, rb = (lin / gx) * 64;
  int which = cb >> 10, cbl = cb & 1023;
  const float* bias = go.bias[which];
  void* Cout = go.out[which];
  int wv = t >> 6, lane = t & 63, l15 = lane & 15, lg = lane >> 4;
  int wc = wv * 32;
  int arow = t >> 2, ach = t & 3;
  int aslot0 = 8 * (ach ^ (arow & 7));
  int aslot1 = 8 * ((ach + 4) ^ (arow & 7));
  int brow = t >> 1, bch = (t & 1) * 4;
  const u16* Ap = A + (size_t)(rb + arow) * HID;
  const u16* Bp = Bt + (size_t)(cb + brow) * HID;
  f32x4 acc[4][2];
  #pragma unroll
  for (int i = 0; i < 4; ++i)
    #pragma unroll
    for (int j = 0; j < 2; ++j) acc[i][j] = (f32x4){0.f, 0.f, 0.f, 0.f};
  short8 pa0 = *reinterpret_cast<const short8*>(&Ap[ach * 8]);
  short8 pa1 = *reinterpret_cast<const short8*>(&Ap[(ach + 4) * 8]);
  short8 pb[4];
  #pragma unroll
  for (int j = 0; j < 4; ++j)
    pb[j] = *reinterpret_cast<const short8*>(&Bp[(bch + j) * 8]);
  for (int kk = 0; kk < HID; kk += 64) {
    __syncthreads();
    *reinterpret_cast<short8*>(&Al[arow * 64 + aslot0]) = pa0;
    *reinterpret_cast<short8*>(&Al[arow * 64 + aslot1]) = pa1;
    #pragma unroll
    for (int j = 0; j < 4; ++j)
      *reinterpret_cast<short8*>(&Bl[brow * 64 + 8 * ((bch + j) ^ (brow & 7))]) = pb[j];
    __syncthreads();
    if (kk + 64 < HID) {
      pa0 = *reinterpret_cast<const short8*>(&Ap[kk + 64 + ach * 8]);
      pa1 = *reinterpret_cast<const short8*>(&Ap[kk + 64 + (ach + 4) * 8]);
      #pragma unroll
      for (int j = 0; j < 4; ++j)
        pb[j] = *reinterpret_cast<const short8*>(&Bp[kk + 64 + (bch + j) * 8]);
    }
    #pragma unroll
    for (int s = 0; s < 2; ++s) {
      short8 am[4], bn[2];
      #pragma unroll
      for (int i = 0; i < 4; ++i) am[i] = swz8(Al, i * 16 + l15, s * 4 + lg);
      #pragma unroll
      for (int j = 0; j < 2; ++j) bn[j] = swz8(Bl, wc + j * 16 + l15, s * 4 + lg);
      #pragma unroll
      for (int i = 0; i < 4; ++i)
        #pragma unroll
        for (int j = 0; j < 2; ++j)
          acc[i][j] = mfma16(am[i], bn[j], acc[i][j]);
    }
  }
  #pragma unroll
  for (int j = 0; j < 2; ++j) {
    float bv = bias[cbl + wc + j * 16 + l15];
    #pragma unroll
    for (int i = 0; i < 4; ++i) {
      #pragma unroll
      for (int r = 0; r < 4; ++r) {
        size_t idx = (size_t)(rb + i * 16 + lg * 4 + r) * HID + cbl + wc + j * 16 + l15;
        float v = acc[i][j][r] + bv;
        if (F32OUT) reinterpret_cast<float*>(Cout)[idx] = v;
        else reinterpret_cast<u16*>(Cout)[idx] = f2b(v);
      }
    }
  }
}

// ---------------- band bias + rank-1 dots (fused), per-tile thread-ordered, PRESCALED ----------------
__global__ __launch_bounds__(256, 3) void bias_kernel(
    const u16* __restrict__ Qb, const u16* __restrict__ Kb,
    const u16* __restrict__ RKb, const u16* __restrict__ RQb,
    u16* __restrict__ bandT, float* __restrict__ qrk0,
    float* __restrict__ krq0) {
  __shared__ u16 smem[20992]; // 41984 B -> 3 blocks/CU
  const int KsO = 0, UO = 4096;
  const int RKO = UO, RQO = UO + 8192;
  const int G1O = UO, G2O = UO + 8448;

  int qt = blockIdx.x;
  int h = blockIdx.y, b = blockIdx.z;
  int q0 = qt * 64;
  int t = threadIdx.x;
  int wv = t >> 6, lane = t & 63, l15 = lane & 15, lg = lane >> 4;
  int qs = q0 + wv * 16;
  int hoff = h * HD;
  int bh = (b * NH + h) * SEQ;

  // ---- fused rank-1 bias for this block's 64 q-rows ----
  {
    int i = q0 + (t >> 2);
    int sub = t & 3;
    size_t rbase = (size_t)(b * SEQ + i) * HID + hoff + sub * 16;
    size_t tb2 = (size_t)hoff + sub * 16;
    float s1 = 0.f, s2 = 0.f;
    #pragma unroll
    for (int c = 0; c < 2; ++c) {
      short8 qv = *reinterpret_cast<const short8*>(&Qb[rbase + c * 8]);
      short8 rv = *reinterpret_cast<const short8*>(&RKb[tb2 + c * 8]);
      short8 kv = *reinterpret_cast<const short8*>(&Kb[rbase + c * 8]);
      short8 uv = *reinterpret_cast<const short8*>(&RQb[tb2 + c * 8]);
      #pragma unroll
      for (int j = 0; j < 8; ++j) {
        s1 += b2f((u16)qv[j]) * b2f((u16)rv[j]);
        s2 += b2f((u16)kv[j]) * b2f((u16)uv[j]);
      }
    }
    s1 += __shfl_xor(s1, 1); s1 += __shfl_xor(s1, 2);
    s2 += __shfl_xor(s2, 1); s2 += __shfl_xor(s2, 2);
    if (sub == 0) { qrk0[bh + i] = s1 * SM_SCALE; krq0[bh + i] = s2 * SM_SCALE; }
  }

  size_t qgrow = (size_t)(b * SEQ + qs + l15) * HID + hoff;
  short8 aq0 = *reinterpret_cast<const short8*>(&Qb[qgrow + lg * 8]);
  short8 aq1 = *reinterpret_cast<const short8*>(&Qb[qgrow + 32 + lg * 8]);

  const f32x4 Z = (f32x4){0.f, 0.f, 0.f, 0.f};
  int vr = t >> 2, vc8 = (t & 3) * 8;
  int ktlo = qt - 8; if (ktlo < 0) ktlo = 0;
  size_t tbase = (((size_t)(b * NH + h) * 32 + qt) * 9) << 12;

  for (int kt = ktlo; kt <= qt; ++kt) {
    int k0 = kt * 64;
    int dt = qt - kt;
    int wlo = 448 - 64 * dt; if (wlo < 0) wlo = 0;
    __syncthreads(); // #1: previous iteration's gathers done
    {
      const u16* kg = &Kb[(size_t)(b * SEQ + k0 + vr) * HID + hoff];
      int c0 = vc8 >> 3;
      *reinterpret_cast<short8*>(&smem[KsO + vr * 64 + 8 * (c0 ^ (vr & 7))]) =
          *reinterpret_cast<const short8*>(&kg[vc8]);
      *reinterpret_cast<short8*>(&smem[KsO + vr * 64 + 8 * ((c0 + 4) ^ (vr & 7))]) =
          *reinterpret_cast<const short8*>(&kg[vc8 + 32]);
    }
    for (int e2 = t; e2 < 1024; e2 += 256) {
      int rr = e2 >> 3, cch = e2 & 7;
      int wr2 = wlo + rr; if (wr2 > 511) wr2 = 511;
      size_t gb = (size_t)wr2 * HID + hoff + cch * 8;
      int slot = 8 * (cch ^ (rr & 7));
      *reinterpret_cast<short8*>(&smem[RKO + rr * 64 + slot]) =
          *reinterpret_cast<const short8*>(&RKb[gb]);
      *reinterpret_cast<short8*>(&smem[RQO + rr * 64 + slot]) =
          *reinterpret_cast<const short8*>(&RQb[gb]);
    }
    __syncthreads(); // #2: staging visible
    u32 g1p[16], g2p[16];
    #pragma unroll
    for (int cw = 0; cw < 8; ++cw) {
      short8 r0 = swz8(&smem[RKO], cw * 16 + l15, lg);
      short8 r1 = swz8(&smem[RKO], cw * 16 + l15, 4 + lg);
      f32x4 g = mfma16(r1, aq1, mfma16(r0, aq0, Z));
      g1p[2 * cw] = pk2(g[0], g[1]);
      g1p[2 * cw + 1] = pk2(g[2], g[3]);
    }
    short8 kw0 = swz8(&smem[KsO], wv * 16 + l15, lg);
    short8 kw1 = swz8(&smem[KsO], wv * 16 + l15, 4 + lg);
    #pragma unroll
    for (int cw = 0; cw < 8; ++cw) {
      short8 u0 = swz8(&smem[RQO], cw * 16 + l15, lg);
      short8 u1 = swz8(&smem[RQO], cw * 16 + l15, 4 + lg);
      f32x4 g = mfma16(u1, kw1, mfma16(u0, kw0, Z));
      g2p[2 * cw] = pk2(g[0], g[1]);
      g2p[2 * cw + 1] = pk2(g[2], g[3]);
    }
    __syncthreads(); // #3: band reads done; U reusable for G
    #pragma unroll
    for (int cw = 0; cw < 8; ++cw) {
      *reinterpret_cast<uint2*>(&smem[G1O + (wv * 16 + l15) * 132 + cw * 16 + lg * 4]) =
          make_uint2(g1p[2 * cw], g1p[2 * cw + 1]);
      *reinterpret_cast<uint2*>(&smem[G2O + (wv * 16 + l15) * 132 + cw * 16 + lg * 4]) =
          make_uint2(g2p[2 * cw], g2p[2 * cw + 1]);
    }
    __syncthreads(); // #4: G visible
    u16* outp = bandT + tbase + ((size_t)dt << 12) + t * 16;
    #pragma unroll
    for (int c = 0; c < 4; ++c) {
      float vv[4];
      #pragma unroll
      for (int r = 0; r < 4; ++r) {
        int q = qs + lg * 4 + r;
        int k = k0 + c * 16 + l15;
        int wi = 511 - (q - k) - wlo; if (wi < 0) wi = 0;
        vv[r] = (b2f(smem[G1O + (wv * 16 + lg * 4 + r) * 132 + wi]) +
                 b2f(smem[G2O + (c * 16 + l15) * 132 + wi])) * SM_SCALE;
      }
      *reinterpret_cast<uint2*>(outp + c * 4) =
          make_uint2(pk2(vv[0], vv[1]), pk2(vv[2], vv[3]));
    }
  }
}

// ---------------- fused DeBERTa flash attention: paired q-tiles + exact defer-rescale ----------------
__global__ __launch_bounds__(256, 2) void attn_mfma(
    const u16* __restrict__ Qb, const u16* __restrict__ Kb,
    const u16* __restrict__ Vb, const float* __restrict__ qrk0,
    const float* __restrict__ krq0, const u16* __restrict__ bandT,
    u16* __restrict__ ATT) {
  __shared__ u16 smem[22016];
  const int KsB[2] = {0, 4096};
  const int VtB[2] = {8192, 12800};
  const int PsO = 17408;

  int qtA = 31 - (int)blockIdx.x; // heavy stream
  int qtB = (int)blockIdx.x;      // light stream (prefix of A's k-range)
  int h = blockIdx.y, b = blockIdx.z;
  int t = threadIdx.x;
  int wv = t >> 6, lane = t & 63, l15 = lane & 15, lg = lane >> 4;
  int hoff = h * HD;
  int bh = (b * NH + h) * SEQ;
  size_t tbaseA = (((size_t)(b * NH + h) * 32 + qtA) * 9) << 12;
  size_t tbaseB = (((size_t)(b * NH + h) * 32 + qtB) * 9) << 12;

  int qsA = qtA * 64 + wv * 16;
  int qsB = qtB * 64 + wv * 16;
  size_t qgA = (size_t)(b * SEQ + qsA + l15) * HID + hoff;
  size_t qgB = (size_t)(b * SEQ + qsB + l15) * HID + hoff;
  short8 aqA0 = *reinterpret_cast<const short8*>(&Qb[qgA + lg * 8]);
  short8 aqA1 = *reinterpret_cast<const short8*>(&Qb[qgA + 32 + lg * 8]);
  short8 aqB0 = *reinterpret_cast<const short8*>(&Qb[qgB + lg * 8]);
  short8 aqB1 = *reinterpret_cast<const short8*>(&Qb[qgB + 32 + lg * 8]);
  float qb0A[4], qb0B[4];
  #pragma unroll
  for (int r = 0; r < 4; ++r) {
    qb0A[r] = qrk0[bh + qsA + lg * 4 + r];
    qb0B[r] = qrk0[bh + qsB + lg * 4 + r];
  }

  float mA[4], lA[4], mB[4], lB[4];
  f32x4 oA[4], oB[4];
  #pragma unroll
  for (int r = 0; r < 4; ++r) { mA[r] = -INFINITY; lA[r] = 0.f; mB[r] = -INFINITY; lB[r] = 0.f; }
  #pragma unroll
  for (int c = 0; c < 4; ++c) {
    oA[c] = (f32x4){0.f, 0.f, 0.f, 0.f};
    oB[c] = (f32x4){0.f, 0.f, 0.f, 0.f};
  }

  const f32x4 Z = (f32x4){0.f, 0.f, 0.f, 0.f};
  int vr = t >> 2, vc8 = (t & 3) * 8;
  int c0s = vc8 >> 3;
  int kslot0 = vr * 64 + 8 * (c0s ^ (vr & 7));
  int kslot1 = vr * 64 + 8 * ((c0s + 4) ^ (vr & 7));
  int vslot[16];
  #pragma unroll
  for (int j = 0; j < 8; ++j) {
    vslot[j] = vrot(vc8 + j, vr);
    vslot[8 + j] = vrot(vc8 + 32 + j, vr);
  }

  // ---- prologue: stage tile 0 into buffer 0 ----
  {
    const u16* kg = &Kb[(size_t)(b * SEQ + vr) * HID + hoff];
    short8 k0v = *reinterpret_cast<const short8*>(&kg[vc8]);
    short8 k1v = *reinterpret_cast<const short8*>(&kg[vc8 + 32]);
    *reinterpret_cast<short8*>(&smem[KsB[0] + kslot0]) = k0v;
    *reinterpret_cast<short8*>(&smem[KsB[0] + kslot1]) = k1v;
    const u16* vg = &Vb[(size_t)(b * SEQ + vr) * HID + hoff];
    short8 v0v = *reinterpret_cast<const short8*>(&vg[vc8]);
    short8 v1v = *reinterpret_cast<const short8*>(&vg[vc8 + 32]);
    #pragma unroll
    for (int j = 0; j < 8; ++j) smem[VtB[0] + vslot[j]] = (u16)v0v[j];
    #pragma unroll
    for (int j = 0; j < 8; ++j) smem[VtB[0] + vslot[8 + j]] = (u16)v1v[j];
  }
  __syncthreads();

  int cur = 0;
  for (int kt = 0; kt <= qtA; ++kt) {
    int k0 = kt * 64;
    int dtA = qtA - kt;
    bool doB = (kt <= qtB);
    int dtB = qtB - kt;
    bool bandedA = (dtA <= 8);
    bool bandedB = doB && (dtB <= 8);
    int ksb = KsB[cur], vtb = VtB[cur];
    int ksn = KsB[cur ^ 1], vtn = VtB[cur ^ 1];

    // ---- early loads: bias tiles (coalesced), kq when needed, next K/V prefetch ----
    short8 pA0, pA1, pB0, pB1;
    if (bandedA) {
      const u16* tb = bandT + tbaseA + ((size_t)dtA << 12) + t * 16;
      pA0 = *reinterpret_cast<const short8*>(tb);
      pA1 = *reinterpret_cast<const short8*>(tb + 8);
    }
    if (bandedB) {
      const u16* tb = bandT + tbaseB + ((size_t)dtB << 12) + t * 16;
      pB0 = *reinterpret_cast<const short8*>(tb);
      pB1 = *reinterpret_cast<const short8*>(tb + 8);
    }
    float kq[4];
    if (dtA > 8 || (doB && dtB > 8)) {
      #pragma unroll
      for (int c = 0; c < 4; ++c) kq[c] = krq0[bh + k0 + c * 16 + l15];
    }
    short8 nk0, nk1, nv0, nv1;
    if (kt < qtA) {
      const u16* kg = &Kb[(size_t)(b * SEQ + k0 + 64 + vr) * HID + hoff];
      nk0 = *reinterpret_cast<const short8*>(&kg[vc8]);
      nk1 = *reinterpret_cast<const short8*>(&kg[vc8 + 32]);
      const u16* vg = &Vb[(size_t)(b * SEQ + k0 + 64 + vr) * HID + hoff];
      nv0 = *reinterpret_cast<const short8*>(&vg[vc8]);
      nv1 = *reinterpret_cast<const short8*>(&vg[vc8 + 32]);
    }

    // ---- K fragments (shared by A and B) ----
    short8 kb0[4], kb1[4];
    #pragma unroll
    for (int c = 0; c < 4; ++c) {
      kb0[c] = swz8(&smem[ksb], c * 16 + l15, lg);
      kb1[c] = swz8(&smem[ksb], c * 16 + l15, 4 + lg);
    }
    f32x4 sA[4], sB[4];
    #pragma unroll
    for (int c = 0; c < 4; ++c)
      sA[c] = mfma16(aqA1, kb1[c], mfma16(aqA0, kb0[c], Z));
    if (doB) {
      #pragma unroll
      for (int c = 0; c < 4; ++c)
        sB[c] = mfma16(aqB1, kb1[c], mfma16(aqB0, kb0[c], Z));
    }
    // ---- bias (prescaled) + fma-scale + mask ----
    #pragma unroll
    for (int c = 0; c < 4; ++c) {
      #pragma unroll
      for (int r = 0; r < 4; ++r) {
        float bbv = bandedA ? b2f((u16)((c < 2 ? pA0 : pA1)[(c & 1) * 4 + r]))
                            : qb0A[r] + kq[c];
        float v = fmaf(sA[c][r], SM_SCALE, bbv);
        if (dtA == 0) {
          int ql = wv * 16 + lg * 4 + r, kl = c * 16 + l15;
          if (ql < kl) v = -INFINITY;
        }
        sA[c][r] = v;
      }
    }
    if (doB) {
      #pragma unroll
      for (int c = 0; c < 4; ++c) {
        #pragma unroll
        for (int r = 0; r < 4; ++r) {
          float bbv = bandedB ? b2f((u16)((c < 2 ? pB0 : pB1)[(c & 1) * 4 + r]))
                              : qb0B[r] + kq[c];
          float v = fmaf(sB[c][r], SM_SCALE, bbv);
          if (dtB == 0) {
            int ql = wv * 16 + lg * 4 + r, kl = c * 16 + l15;
            if (ql < kl) v = -INFINITY;
          }
          sB[c][r] = v;
        }
      }
    }
    // ---- softmax A: tile max, exact defer-rescale, exp-sum ----
    {
      float mn[4];
      #pragma unroll
      for (int r = 0; r < 4; ++r) {
        float mx = fmaxf(fmaxf(sA[0][r], sA[1][r]), fmaxf(sA[2][r], sA[3][r]));
        mx = rmax16(mx);
        mn[r] = fmaxf(mA[r], mx);
      }
      bool sk = (mn[0] == mA[0]) && (mn[1] == mA[1]) &&
                (mn[2] == mA[2]) && (mn[3] == mA[3]);
      if (!__all(sk)) {
        #pragma unroll
        for (int r = 0; r < 4; ++r) {
          float al = __expf(mA[r] - mn[r]); // 1.0 when unchanged
          lA[r] *= al;
          mA[r] = mn[r];
          #pragma unroll
          for (int c = 0; c < 4; ++c) oA[c][r] *= al;
        }
      }
      #pragma unroll
      for (int r = 0; r < 4; ++r) {
        float ps = 0.f;
        #pragma unroll
        for (int c = 0; c < 4; ++c) {
          float p = __expf(sA[c][r] - mA[r]);
          sA[c][r] = p;
          ps += p;
        }
        ps = rsum16(ps);
        lA[r] += ps;
      }
    }
    // ---- softmax B ----
    if (doB) {
      float mn[4];
      #pragma unroll
      for (int r = 0; r < 4; ++r) {
        float mx = fmaxf(fmaxf(sB[0][r], sB[1][r]), fmaxf(sB[2][r], sB[3][r]));
        mx = rmax16(mx);
        mn[r] = fmaxf(mB[r], mx);
      }
      bool sk = (mn[0] == mB[0]) && (mn[1] == mB[1]) &&
                (mn[2] == mB[2]) && (mn[3] == mB[3]);
      if (!__all(sk)) {
        #pragma unroll
        for (int r = 0; r < 4; ++r) {
          float al = __expf(mB[r] - mn[r]);
          lB[r] *= al;
          mB[r] = mn[r];
          #pragma unroll
          for (int c = 0; c < 4; ++c) oB[c][r] *= al;
        }
      }
      #pragma unroll
      for (int r = 0; r < 4; ++r) {
        float ps = 0.f;
        #pragma unroll
        for (int c = 0; c < 4; ++c) {
          float p = __expf(sB[c][r] - mB[r]);
          sB[c][r] = p;
          ps += p;
        }
        ps = rsum16(ps);
        lB[r] += ps;
      }
    }
    // ---- V fragments (shared) ----
    short8 vb0[4], vb1[4];
    #pragma unroll
    for (int c = 0; c < 4; ++c) {
      int n = c * 16 + l15;
      vb0[c] = *reinterpret_cast<const short8*>(&smem[vtb + vrot(n, lg * 8)]);
      vb1[c] = *reinterpret_cast<const short8*>(&smem[vtb + vrot(n, 32 + lg * 8)]);
    }
    // ---- PV A ----
    #pragma unroll
    for (int c = 0; c < 4; ++c)
      #pragma unroll
      for (int r = 0; r < 4; ++r)
        smem[PsO + vrot(wv * 16 + lg * 4 + r, c * 16 + l15)] = f2b(sA[c][r]);
    int prow = wv * 16 + l15;
    {
      short8 ap0 = *reinterpret_cast<const short8*>(&smem[PsO + vrot(prow, lg * 8)]);
      short8 ap1 = *reinterpret_cast<const short8*>(&smem[PsO + vrot(prow, 32 + lg * 8)]);
      #pragma unroll
      for (int c = 0; c < 4; ++c)
        oA[c] = mfma16(ap1, vb1[c], mfma16(ap0, vb0[c], oA[c]));
    }
    // ---- PV B (same Ps rows reused; same-wave ordering) ----
    if (doB) {
      #pragma unroll
      for (int c = 0; c < 4; ++c)
        #pragma unroll
        for (int r = 0; r < 4; ++r)
          smem[PsO + vrot(wv * 16 + lg * 4 + r, c * 16 + l15)] = f2b(sB[c][r]);
      short8 bp0 = *reinterpret_cast<const short8*>(&smem[PsO + vrot(prow, lg * 8)]);
      short8 bp1 = *reinterpret_cast<const short8*>(&smem[PsO + vrot(prow, 32 + lg * 8)]);
      #pragma unroll
      for (int c = 0; c < 4; ++c)
        oB[c] = mfma16(bp1, vb1[c], mfma16(bp0, vb0[c], oB[c]));
    }
    // ---- write prefetched tile into the other buffer ----
    if (kt < qtA) {
      *reinterpret_cast<short8*>(&smem[ksn + kslot0]) = nk0;
      *reinterpret_cast<short8*>(&smem[ksn + kslot1]) = nk1;
      #pragma unroll
      for (int j = 0; j < 8; ++j) smem[vtn + vslot[j]] = (u16)nv0[j];
      #pragma unroll
      for (int j = 0; j < 8; ++j) smem[vtn + vslot[8 + j]] = (u16)nv1[j];
    }
    __syncthreads(); // single barrier per tile
    cur ^= 1;
  }
  #pragma unroll
  for (int r = 0; r < 4; ++r) { lA[r] = 1.0f / lA[r]; lB[r] = 1.0f / lB[r]; }
  #pragma unroll
  for (int c = 0; c < 4; ++c) {
    #pragma unroll
    for (int r = 0; r < 4; ++r) {
      size_t obA = (size_t)(b * SEQ + qsA + lg * 4 + r) * HID + hoff + c * 16 + l15;
      ATT[obA] = f2b(oA[c][r] * lA[r]);
      size_t obB = (size_t)(b * SEQ + qsB + lg * 4 + r) * HID + hoff + c * 16 + l15;
      ATT[obB] = f2b(oB[c][r] * lB[r]);
    }
  }
}

extern "C" void kernel_launch(void* const* d_in, const int* in_sizes, int n_in,
                              void* d_out, int out_size, void* d_ws, size_t ws_size,
                              hipStream_t stream) {
  const float* x      = (const float*)d_in[0];
  const float* Wq     = (const float*)d_in[1];
  const float* bq     = (const float*)d_in[2];
  const float* Wk     = (const float*)d_in[3];
  const float* bk     = (const float*)d_in[4];
  const float* Wv     = (const float*)d_in[5];
  const float* bv     = (const float*)d_in[6];
  const float* Wo     = (const float*)d_in[7];
  const float* bo     = (const float*)d_in[8];
  const float* relpos = (const float*)d_in[9];
  const float* gamma  = (const float*)d_in[10];
  const float* beta   = (const float*)d_in[11];
  const float* Wrk    = (const float*)d_in[12];
  const float* brk    = (const float*)d_in[13];
  const float* Wrq    = (const float*)d_in[14];
  const float* brq    = (const float*)d_in[15];
  float* out = (float*)d_out;

  u16* wsu = (u16*)d_ws;
  size_t off = 0;
  auto alloc = [&](size_t n) { u16* p = wsu + off; off += n; return p; };
  u16* xb   = alloc(4194304);
  u16* Eb   = alloc(524288);
  u16* WtQ  = alloc(1048576);  // contiguous: WtQ|WtK|WtV for merged QKV GEMM
  u16* WtK  = alloc(1048576);
  u16* WtV  = alloc(1048576);
  u16* WtO  = alloc(1048576);
  u16* WtRK = alloc(1048576);  // contiguous: WtRK|WtRQ for merged rel GEMM
  u16* WtRQ = alloc(1048576);
  u16* Qb2  = alloc(4194304);
  u16* Kb2  = alloc(4194304);
  u16* Vb2  = alloc(4194304);
  u16* ATTb = alloc(4194304);
  u16* RKb2 = alloc(524288);
  u16* RQb2 = alloc(524288);
  float* qrk0 = (float*)(wsu + off); off += 131072;
  float* krq0 = (float*)(wsu + off); off += 131072;
  u16* bandT = alloc((size_t)NB * NH * 32 * 9 * 4096); // 75.5 MB tile-layout bias

  PrepArgs pa;
  pa.tbl = relpos; pa.gamma = gamma; pa.beta = beta; pa.e = Eb;
  pa.x = x; pa.xb = xb;
  pa.ws[0] = Wq; pa.ws[1] = Wk; pa.ws[2] = Wv; pa.ws[3] = Wo; pa.ws[4] = Wrk; pa.ws[5] = Wrq;
  pa.wd[0] = WtQ; pa.wd[1] = WtK; pa.wd[2] = WtV; pa.wd[3] = WtO; pa.wd[4] = WtRK; pa.wd[5] = WtRQ;
  prep_kernel<<<8704, 256, 0, stream>>>(pa);

  GO goQKV = {{bq, bk, bv}, {Qb2, Kb2, Vb2}};
  dim3 gQKV(24, 32); // 768 blocks (%8==0) -> 3 blocks/CU, XCD-chunked
  gemm_bf16<false><<<gQKV, 512, 0, stream>>>(xb, WtQ, goQKV);
  GO goRel = {{brk, brq, brq}, {RKb2, RQb2, RQb2}};
  dim3 gRel2(16, 8); // m64: 128 blocks (%8==0)
  gemm_m64<false><<<gRel2, 256, 0, stream>>>(Eb, WtRK, goRel);

  dim3 gB(32, NH, NB);
  bias_kernel<<<gB, 256, 0, stream>>>(Qb2, Kb2, RKb2, RQb2, bandT, qrk0, krq0);

  dim3 gA(16, NH, NB); // paired q-tiles: 512 balanced blocks
  attn_mfma<<<gA, 256, 0, stream>>>(Qb2, Kb2, Vb2, qrk0, krq0, bandT, ATTb);

  GO goOut = {{bo, bo, bo}, {out, out, out}};
  dim3 gOut(8, 64); // m64: 512 blocks (%8==0) -> 2 blocks/CU
  gemm_m64<true><<<gOut, 256, 0, stream>>>(ATTb, WtO, goOut);
}

// Round 15
// 210.669 us; speedup vs baseline: 1.0893x; 1.0219x over previous
//
#include <hip/hip_runtime.h>
#include <math.h>

#define NH 16
#define HD 64
#define HID 1024
#define SEQ 2048
#define NB 2

typedef __attribute__((ext_vector_type(8))) short short8;
typedef __attribute__((ext_vector_type(4))) float f32x4;
typedef unsigned short u16;
typedef unsigned int u32;

constexpr float LN_EPS_C = 1e-5f;
constexpr float SM_SCALE = 0.07216878364870323f; // 1/sqrt(64*3)

__device__ inline u16 f2b(float f) {
  unsigned u = __builtin_bit_cast(unsigned, f);
  u = (u + 0x7FFFu + ((u >> 16) & 1u)) >> 16;
  return (u16)u;
}
__device__ inline float b2f(u16 h) {
  unsigned u = ((unsigned)h) << 16;
  return __builtin_bit_cast(float, u);
}
__device__ inline u32 pk2(float lo, float hi) {
  return (u32)f2b(lo) | ((u32)f2b(hi) << 16);
}
__device__ inline f32x4 mfma16(short8 a, short8 b, f32x4 c) {
  return __builtin_amdgcn_mfma_f32_16x16x32_bf16(a, b, c, 0, 0, 0);
}
// swizzled read of a [rows][64] bf16 tile whose writes used slot = chunk^(row&7)
__device__ inline short8 swz8(const u16* base, int row, int hc) {
  return *reinterpret_cast<const short8*>(&base[row * 64 + 8 * (hc ^ (row & 7))]);
}
// add-rotate swizzle for [64 row][72-stride] tiles, col in [0,64).
__device__ inline int vrot(int row, int col) {
  return row * 72 + ((col + 16 * ((row >> 3) & 3)) & 63);
}
// DPP row-rotate reduction within the 16-lane row group
template <int N>
__device__ inline float rorf(float x) {
  return __builtin_bit_cast(float,
      __builtin_amdgcn_update_dpp(0, __builtin_bit_cast(int, x),
                                  0x120 + N, 0xF, 0xF, true));
}
__device__ inline float rmax16(float x) {
  x = fmaxf(x, rorf<1>(x)); x = fmaxf(x, rorf<2>(x));
  x = fmaxf(x, rorf<4>(x)); x = fmaxf(x, rorf<8>(x));
  return x;
}
__device__ inline float rsum16(float x) {
  x += rorf<1>(x); x += rorf<2>(x); x += rorf<4>(x); x += rorf<8>(x);
  return x;
}

// ---------------- fused preprocessing: ln | f32->bf16 conv | 6x weight transpose ----------------
struct PrepArgs {
  const float* tbl; const float* gamma; const float* beta; u16* e;
  const float* x; u16* xb;
  const float* ws[6]; u16* wd[6];
};
__global__ __launch_bounds__(256) void prep_kernel(PrepArgs p) {
  __shared__ float T[32][33];
  __shared__ float sb[4], ssb[4];
  int bid = blockIdx.x;
  int t = threadIdx.x;
  if (bid < 512) {
    // LayerNorm over relpos_table row -> bf16
    int row = bid;
    const float4* rp = reinterpret_cast<const float4*>(p.tbl + (size_t)row * HID);
    float4 x = rp[t];
    float s = x.x + x.y + x.z + x.w;
    float ss = x.x * x.x + x.y * x.y + x.z * x.z + x.w * x.w;
    #pragma unroll
    for (int o = 1; o < 64; o <<= 1) {
      s += __shfl_xor(s, o);
      ss += __shfl_xor(ss, o);
    }
    int w = t >> 6;
    if ((t & 63) == 0) { sb[w] = s; ssb[w] = ss; }
    __syncthreads();
    s = sb[0] + sb[1] + sb[2] + sb[3];
    ss = ssb[0] + ssb[1] + ssb[2] + ssb[3];
    float mu = s * (1.0f / HID);
    float var = ss * (1.0f / HID) - mu * mu;
    float rs = rsqrtf(var + LN_EPS_C);
    float4 g = reinterpret_cast<const float4*>(p.gamma)[t];
    float4 bt = reinterpret_cast<const float4*>(p.beta)[t];
    ushort4 o4;
    o4.x = f2b((x.x - mu) * rs * g.x + bt.x);
    o4.y = f2b((x.y - mu) * rs * g.y + bt.y);
    o4.z = f2b((x.z - mu) * rs * g.z + bt.z);
    o4.w = f2b((x.w - mu) * rs * g.w + bt.w);
    *reinterpret_cast<ushort4*>(&p.e[(size_t)row * HID + t * 4]) = o4;
  } else if (bid < 2560) {
    // x f32 -> bf16
    int i = ((bid - 512) * 256 + t) * 8;
    float4 a = *reinterpret_cast<const float4*>(&p.x[i]);
    float4 c = *reinterpret_cast<const float4*>(&p.x[i + 4]);
    short8 o;
    o[0] = (short)f2b(a.x); o[1] = (short)f2b(a.y); o[2] = (short)f2b(a.z); o[3] = (short)f2b(a.w);
    o[4] = (short)f2b(c.x); o[5] = (short)f2b(c.y); o[6] = (short)f2b(c.z); o[7] = (short)f2b(c.w);
    *reinterpret_cast<short8*>(&p.xb[i]) = o;
  } else {
    // W[k][n] f32 -> Wt[n][k] bf16
    int z = (bid - 2560) >> 10;
    int rem = (bid - 2560) & 1023;
    int bn = (rem & 31) * 32, bk = (rem >> 5) * 32;
    const float* W = p.ws[z];
    u16* Wt = p.wd[z];
    int r = t >> 3, c4 = (t & 7) * 4;
    float4 v = *reinterpret_cast<const float4*>(&W[(size_t)(bk + r) * HID + bn + c4]);
    T[r][c4 + 0] = v.x; T[r][c4 + 1] = v.y; T[r][c4 + 2] = v.z; T[r][c4 + 3] = v.w;
    __syncthreads();
    int n = t >> 3, k4 = (t & 7) * 4;
    ushort4 o;
    o.x = f2b(T[k4 + 0][n]); o.y = f2b(T[k4 + 1][n]);
    o.z = f2b(T[k4 + 2][n]); o.w = f2b(T[k4 + 3][n]);
    *reinterpret_cast<ushort4*>(&Wt[(size_t)(bn + n) * HID + bk + k4]) = o;
  }
}

// ---------------- bf16 MFMA GEMM: 512 threads, 128x128, BK=64, XCD swizzle ----------------
struct GO {
  const float* bias[3];
  void* out[3];
};
template <bool F32OUT>
__global__ __launch_bounds__(512) void gemm_bf16(const u16* __restrict__ A,
    const u16* __restrict__ Bt, GO go) {
  __shared__ u16 Al[8192]; // [128][64] swizzled
  __shared__ u16 Bl[8192];
  int t = threadIdx.x;
  int gx = gridDim.x;
  int nwg = gx * gridDim.y;
  int lin = blockIdx.y * gx + blockIdx.x;
  lin = (lin & 7) * (nwg >> 3) + (lin >> 3); // bijective (nwg % 8 == 0)
  int cb = (lin % gx) * 128, rb = (lin / gx) * 128;
  int which = cb >> 10, cbl = cb & 1023;
  const float* bias = go.bias[which];
  void* Cout = go.out[which];
  int wv = t >> 6, lane = t & 63, l15 = lane & 15, lg = lane >> 4;
  int wr = (wv >> 2) * 64, wc = (wv & 3) * 32;
  int srow = t >> 2, sch = t & 3;
  f32x4 acc[4][2];
  #pragma unroll
  for (int i = 0; i < 4; ++i)
    #pragma unroll
    for (int j = 0; j < 2; ++j) acc[i][j] = (f32x4){0.f, 0.f, 0.f, 0.f};
  const u16* Ap = A + (size_t)(rb + srow) * HID;
  const u16* Bp = Bt + (size_t)(cb + srow) * HID;
  int slot0 = 8 * (sch ^ (srow & 7));
  int slot1 = 8 * ((sch + 4) ^ (srow & 7));
  short8 pa0 = *reinterpret_cast<const short8*>(&Ap[sch * 8]);
  short8 pa1 = *reinterpret_cast<const short8*>(&Ap[(sch + 4) * 8]);
  short8 pb0 = *reinterpret_cast<const short8*>(&Bp[sch * 8]);
  short8 pb1 = *reinterpret_cast<const short8*>(&Bp[(sch + 4) * 8]);
  for (int kk = 0; kk < HID; kk += 64) {
    __syncthreads();
    *reinterpret_cast<short8*>(&Al[srow * 64 + slot0]) = pa0;
    *reinterpret_cast<short8*>(&Al[srow * 64 + slot1]) = pa1;
    *reinterpret_cast<short8*>(&Bl[srow * 64 + slot0]) = pb0;
    *reinterpret_cast<short8*>(&Bl[srow * 64 + slot1]) = pb1;
    __syncthreads();
    if (kk + 64 < HID) {
      pa0 = *reinterpret_cast<const short8*>(&Ap[kk + 64 + sch * 8]);
      pa1 = *reinterpret_cast<const short8*>(&Ap[kk + 64 + (sch + 4) * 8]);
      pb0 = *reinterpret_cast<const short8*>(&Bp[kk + 64 + sch * 8]);
      pb1 = *reinterpret_cast<const short8*>(&Bp[kk + 64 + (sch + 4) * 8]);
    }
    #pragma unroll
    for (int s = 0; s < 2; ++s) {
      short8 am[4], bn[2];
      #pragma unroll
      for (int i = 0; i < 4; ++i) am[i] = swz8(Al, wr + i * 16 + l15, s * 4 + lg);
      #pragma unroll
      for (int j = 0; j < 2; ++j) bn[j] = swz8(Bl, wc + j * 16 + l15, s * 4 + lg);
      #pragma unroll
      for (int i = 0; i < 4; ++i)
        #pragma unroll
        for (int j = 0; j < 2; ++j)
          acc[i][j] = mfma16(am[i], bn[j], acc[i][j]);
    }
  }
  #pragma unroll
  for (int j = 0; j < 2; ++j) {
    float bv = bias[cbl + wc + j * 16 + l15];
    #pragma unroll
    for (int i = 0; i < 4; ++i) {
      #pragma unroll
      for (int r = 0; r < 4; ++r) {
        size_t idx = (size_t)(rb + wr + i * 16 + lg * 4 + r) * HID + cbl + wc + j * 16 + l15;
        float v = acc[i][j][r] + bv;
        if (F32OUT) reinterpret_cast<float*>(Cout)[idx] = v;
        else reinterpret_cast<u16*>(Cout)[idx] = f2b(v);
      }
    }
  }
}

// ---------------- bf16 MFMA GEMM: 256 threads, 64x128 tile, XCD swizzle ----------------
template <bool F32OUT>
__global__ __launch_bounds__(256) void gemm_m64(const u16* __restrict__ A,
    const u16* __restrict__ Bt, GO go) {
  __shared__ u16 Al[4096]; // [64][64] swizzled
  __shared__ u16 Bl[8192]; // [128][64] swizzled
  int t = threadIdx.x;
  int gx = gridDim.x;
  int nwg = gx * gridDim.y;
  int lin = blockIdx.y * gx + blockIdx.x;
  lin = (lin & 7) * (nwg >> 3) + (lin >> 3); // bijective (nwg % 8 == 0)
  int cb = (lin % gx) * 128, rb = (lin / gx) * 64;
  int which = cb >> 10, cbl = cb & 1023;
  const float* bias = go.bias[which];
  void* Cout = go.out[which];
  int wv = t >> 6, lane = t & 63, l15 = lane & 15, lg = lane >> 4;
  int wc = wv * 32;
  int arow = t >> 2, ach = t & 3;
  int aslot0 = 8 * (ach ^ (arow & 7));
  int aslot1 = 8 * ((ach + 4) ^ (arow & 7));
  int brow = t >> 1, bch = (t & 1) * 4;
  const u16* Ap = A + (size_t)(rb + arow) * HID;
  const u16* Bp = Bt + (size_t)(cb + brow) * HID;
  f32x4 acc[4][2];
  #pragma unroll
  for (int i = 0; i < 4; ++i)
    #pragma unroll
    for (int j = 0; j < 2; ++j) acc[i][j] = (f32x4){0.f, 0.f, 0.f, 0.f};
  short8 pa0 = *reinterpret_cast<const short8*>(&Ap[ach * 8]);
  short8 pa1 = *reinterpret_cast<const short8*>(&Ap[(ach + 4) * 8]);
  short8 pb[4];
  #pragma unroll
  for (int j = 0; j < 4; ++j)
    pb[j] = *reinterpret_cast<const short8*>(&Bp[(bch + j) * 8]);
  for (int kk = 0; kk < HID; kk += 64) {
    __syncthreads();
    *reinterpret_cast<short8*>(&Al[arow * 64 + aslot0]) = pa0;
    *reinterpret_cast<short8*>(&Al[arow * 64 + aslot1]) = pa1;
    #pragma unroll
    for (int j = 0; j < 4; ++j)
      *reinterpret_cast<short8*>(&Bl[brow * 64 + 8 * ((bch + j) ^ (brow & 7))]) = pb[j];
    __syncthreads();
    if (kk + 64 < HID) {
      pa0 = *reinterpret_cast<const short8*>(&Ap[kk + 64 + ach * 8]);
      pa1 = *reinterpret_cast<const short8*>(&Ap[kk + 64 + (ach + 4) * 8]);
      #pragma unroll
      for (int j = 0; j < 4; ++j)
        pb[j] = *reinterpret_cast<const short8*>(&Bp[kk + 64 + (bch + j) * 8]);
    }
    #pragma unroll
    for (int s = 0; s < 2; ++s) {
      short8 am[4], bn[2];
      #pragma unroll
      for (int i = 0; i < 4; ++i) am[i] = swz8(Al, i * 16 + l15, s * 4 + lg);
      #pragma unroll
      for (int j = 0; j < 2; ++j) bn[j] = swz8(Bl, wc + j * 16 + l15, s * 4 + lg);
      #pragma unroll
      for (int i = 0; i < 4; ++i)
        #pragma unroll
        for (int j = 0; j < 2; ++j)
          acc[i][j] = mfma16(am[i], bn[j], acc[i][j]);
    }
  }
  #pragma unroll
  for (int j = 0; j < 2; ++j) {
    float bv = bias[cbl + wc + j * 16 + l15];
    #pragma unroll
    for (int i = 0; i < 4; ++i) {
      #pragma unroll
      for (int r = 0; r < 4; ++r) {
        size_t idx = (size_t)(rb + i * 16 + lg * 4 + r) * HID + cbl + wc + j * 16 + l15;
        float v = acc[i][j][r] + bv;
        if (F32OUT) reinterpret_cast<float*>(Cout)[idx] = v;
        else reinterpret_cast<u16*>(Cout)[idx] = f2b(v);
      }
    }
  }
}

// ---------------- band bias + rank-1 dots (fused), per-tile thread-ordered, PRESCALED ----------------
__global__ __launch_bounds__(256, 3) void bias_kernel(
    const u16* __restrict__ Qb, const u16* __restrict__ Kb,
    const u16* __restrict__ RKb, const u16* __restrict__ RQb,
    u16* __restrict__ bandT, float* __restrict__ qrk0,
    float* __restrict__ krq0) {
  __shared__ u16 smem[20992]; // 41984 B -> 3 blocks/CU
  const int KsO = 0, UO = 4096;
  const int RKO = UO, RQO = UO + 8192;
  const int G1O = UO, G2O = UO + 8448;

  int qt = blockIdx.x;
  int h = blockIdx.y, b = blockIdx.z;
  int q0 = qt * 64;
  int t = threadIdx.x;
  int wv = t >> 6, lane = t & 63, l15 = lane & 15, lg = lane >> 4;
  int qs = q0 + wv * 16;
  int hoff = h * HD;
  int bh = (b * NH + h) * SEQ;

  // ---- fused rank-1 bias for this block's 64 q-rows ----
  {
    int i = q0 + (t >> 2);
    int sub = t & 3;
    size_t rbase = (size_t)(b * SEQ + i) * HID + hoff + sub * 16;
    size_t tb2 = (size_t)hoff + sub * 16;
    float s1 = 0.f, s2 = 0.f;
    #pragma unroll
    for (int c = 0; c < 2; ++c) {
      short8 qv = *reinterpret_cast<const short8*>(&Qb[rbase + c * 8]);
      short8 rv = *reinterpret_cast<const short8*>(&RKb[tb2 + c * 8]);
      short8 kv = *reinterpret_cast<const short8*>(&Kb[rbase + c * 8]);
      short8 uv = *reinterpret_cast<const short8*>(&RQb[tb2 + c * 8]);
      #pragma unroll
      for (int j = 0; j < 8; ++j) {
        s1 += b2f((u16)qv[j]) * b2f((u16)rv[j]);
        s2 += b2f((u16)kv[j]) * b2f((u16)uv[j]);
      }
    }
    s1 += __shfl_xor(s1, 1); s1 += __shfl_xor(s1, 2);
    s2 += __shfl_xor(s2, 1); s2 += __shfl_xor(s2, 2);
    if (sub == 0) { qrk0[bh + i] = s1 * SM_SCALE; krq0[bh + i] = s2 * SM_SCALE; }
  }

  size_t qgrow = (size_t)(b * SEQ + qs + l15) * HID + hoff;
  short8 aq0 = *reinterpret_cast<const short8*>(&Qb[qgrow + lg * 8]);
  short8 aq1 = *reinterpret_cast<const short8*>(&Qb[qgrow + 32 + lg * 8]);

  const f32x4 Z = (f32x4){0.f, 0.f, 0.f, 0.f};
  int vr = t >> 2, vc8 = (t & 3) * 8;
  int ktlo = qt - 8; if (ktlo < 0) ktlo = 0;
  size_t tbase = (((size_t)(b * NH + h) * 32 + qt) * 9) << 12;

  for (int kt = ktlo; kt <= qt; ++kt) {
    int k0 = kt * 64;
    int dt = qt - kt;
    int wlo = 448 - 64 * dt; if (wlo < 0) wlo = 0;
    __syncthreads(); // #1: previous iteration's gathers done
    {
      const u16* kg = &Kb[(size_t)(b * SEQ + k0 + vr) * HID + hoff];
      int c0 = vc8 >> 3;
      *reinterpret_cast<short8*>(&smem[KsO + vr * 64 + 8 * (c0 ^ (vr & 7))]) =
          *reinterpret_cast<const short8*>(&kg[vc8]);
      *reinterpret_cast<short8*>(&smem[KsO + vr * 64 + 8 * ((c0 + 4) ^ (vr & 7))]) =
          *reinterpret_cast<const short8*>(&kg[vc8 + 32]);
    }
    for (int e2 = t; e2 < 1024; e2 += 256) {
      int rr = e2 >> 3, cch = e2 & 7;
      int wr2 = wlo + rr; if (wr2 > 511) wr2 = 511;
      size_t gb = (size_t)wr2 * HID + hoff + cch * 8;
      int slot = 8 * (cch ^ (rr & 7));
      *reinterpret_cast<short8*>(&smem[RKO + rr * 64 + slot]) =
          *reinterpret_cast<const short8*>(&RKb[gb]);
      *reinterpret_cast<short8*>(&smem[RQO + rr * 64 + slot]) =
          *reinterpret_cast<const short8*>(&RQb[gb]);
    }
    __syncthreads(); // #2: staging visible
    u32 g1p[16], g2p[16];
    #pragma unroll
    for (int cw = 0; cw < 8; ++cw) {
      short8 r0 = swz8(&smem[RKO], cw * 16 + l15, lg);
      short8 r1 = swz8(&smem[RKO], cw * 16 + l15, 4 + lg);
      f32x4 g = mfma16(r1, aq1, mfma16(r0, aq0, Z));
      g1p[2 * cw] = pk2(g[0], g[1]);
      g1p[2 * cw + 1] = pk2(g[2], g[3]);
    }
    short8 kw0 = swz8(&smem[KsO], wv * 16 + l15, lg);
    short8 kw1 = swz8(&smem[KsO], wv * 16 + l15, 4 + lg);
    #pragma unroll
    for (int cw = 0; cw < 8; ++cw) {
      short8 u0 = swz8(&smem[RQO], cw * 16 + l15, lg);
      short8 u1 = swz8(&smem[RQO], cw * 16 + l15, 4 + lg);
      f32x4 g = mfma16(u1, kw1, mfma16(u0, kw0, Z));
      g2p[2 * cw] = pk2(g[0], g[1]);
      g2p[2 * cw + 1] = pk2(g[2], g[3]);
    }
    __syncthreads(); // #3: band reads done; U reusable for G
    #pragma unroll
    for (int cw = 0; cw < 8; ++cw) {
      *reinterpret_cast<uint2*>(&smem[G1O + (wv * 16 + l15) * 132 + cw * 16 + lg * 4]) =
          make_uint2(g1p[2 * cw], g1p[2 * cw + 1]);
      *reinterpret_cast<uint2*>(&smem[G2O + (wv * 16 + l15) * 132 + cw * 16 + lg * 4]) =
          make_uint2(g2p[2 * cw], g2p[2 * cw + 1]);
    }
    __syncthreads(); // #4: G visible
    u16* outp = bandT + tbase + ((size_t)dt << 12) + t * 16;
    #pragma unroll
    for (int c = 0; c < 4; ++c) {
      float vv[4];
      #pragma unroll
      for (int r = 0; r < 4; ++r) {
        int q = qs + lg * 4 + r;
        int k = k0 + c * 16 + l15;
        int wi = 511 - (q - k) - wlo; if (wi < 0) wi = 0;
        vv[r] = (b2f(smem[G1O + (wv * 16 + lg * 4 + r) * 132 + wi]) +
                 b2f(smem[G2O + (c * 16 + l15) * 132 + wi])) * SM_SCALE;
      }
      *reinterpret_cast<uint2*>(outp + c * 4) =
          make_uint2(pk2(vv[0], vv[1]), pk2(vv[2], vv[3]));
    }
  }
}

// ---------------- fused DeBERTa flash attention: paired q-tiles, setprio MFMA ----------------
__global__ __launch_bounds__(256, 2) void attn_mfma(
    const u16* __restrict__ Qb, const u16* __restrict__ Kb,
    const u16* __restrict__ Vb, const float* __restrict__ qrk0,
    const float* __restrict__ krq0, const u16* __restrict__ bandT,
    u16* __restrict__ ATT) {
  __shared__ u16 smem[22016];
  const int KsB[2] = {0, 4096};
  const int VtB[2] = {8192, 12800};
  const int PsO = 17408;

  int qtA = 31 - (int)blockIdx.x; // heavy stream
  int qtB = (int)blockIdx.x;      // light stream (prefix of A's k-range)
  int h = blockIdx.y, b = blockIdx.z;
  int t = threadIdx.x;
  int wv = t >> 6, lane = t & 63, l15 = lane & 15, lg = lane >> 4;
  int hoff = h * HD;
  int bh = (b * NH + h) * SEQ;
  size_t tbaseA = (((size_t)(b * NH + h) * 32 + qtA) * 9) << 12;
  size_t tbaseB = (((size_t)(b * NH + h) * 32 + qtB) * 9) << 12;

  int qsA = qtA * 64 + wv * 16;
  int qsB = qtB * 64 + wv * 16;
  size_t qgA = (size_t)(b * SEQ + qsA + l15) * HID + hoff;
  size_t qgB = (size_t)(b * SEQ + qsB + l15) * HID + hoff;
  short8 aqA0 = *reinterpret_cast<const short8*>(&Qb[qgA + lg * 8]);
  short8 aqA1 = *reinterpret_cast<const short8*>(&Qb[qgA + 32 + lg * 8]);
  short8 aqB0 = *reinterpret_cast<const short8*>(&Qb[qgB + lg * 8]);
  short8 aqB1 = *reinterpret_cast<const short8*>(&Qb[qgB + 32 + lg * 8]);
  float qb0A[4], qb0B[4];
  #pragma unroll
  for (int r = 0; r < 4; ++r) {
    qb0A[r] = qrk0[bh + qsA + lg * 4 + r];
    qb0B[r] = qrk0[bh + qsB + lg * 4 + r];
  }

  float mA[4], lA[4], mB[4], lB[4];
  f32x4 oA[4], oB[4];
  #pragma unroll
  for (int r = 0; r < 4; ++r) { mA[r] = -INFINITY; lA[r] = 0.f; mB[r] = -INFINITY; lB[r] = 0.f; }
  #pragma unroll
  for (int c = 0; c < 4; ++c) {
    oA[c] = (f32x4){0.f, 0.f, 0.f, 0.f};
    oB[c] = (f32x4){0.f, 0.f, 0.f, 0.f};
  }

  const f32x4 Z = (f32x4){0.f, 0.f, 0.f, 0.f};
  int vr = t >> 2, vc8 = (t & 3) * 8;
  int c0s = vc8 >> 3;
  int kslot0 = vr * 64 + 8 * (c0s ^ (vr & 7));
  int kslot1 = vr * 64 + 8 * ((c0s + 4) ^ (vr & 7));
  int vslot[16];
  #pragma unroll
  for (int j = 0; j < 8; ++j) {
    vslot[j] = vrot(vc8 + j, vr);
    vslot[8 + j] = vrot(vc8 + 32 + j, vr);
  }

  // ---- prologue: stage tile 0 into buffer 0 ----
  {
    const u16* kg = &Kb[(size_t)(b * SEQ + vr) * HID + hoff];
    short8 k0v = *reinterpret_cast<const short8*>(&kg[vc8]);
    short8 k1v = *reinterpret_cast<const short8*>(&kg[vc8 + 32]);
    *reinterpret_cast<short8*>(&smem[KsB[0] + kslot0]) = k0v;
    *reinterpret_cast<short8*>(&smem[KsB[0] + kslot1]) = k1v;
    const u16* vg = &Vb[(size_t)(b * SEQ + vr) * HID + hoff];
    short8 v0v = *reinterpret_cast<const short8*>(&vg[vc8]);
    short8 v1v = *reinterpret_cast<const short8*>(&vg[vc8 + 32]);
    #pragma unroll
    for (int j = 0; j < 8; ++j) smem[VtB[0] + vslot[j]] = (u16)v0v[j];
    #pragma unroll
    for (int j = 0; j < 8; ++j) smem[VtB[0] + vslot[8 + j]] = (u16)v1v[j];
  }
  __syncthreads();

  int cur = 0;
  for (int kt = 0; kt <= qtA; ++kt) {
    int k0 = kt * 64;
    int dtA = qtA - kt;
    bool doB = (kt <= qtB);
    int dtB = qtB - kt;
    bool bandedA = (dtA <= 8);
    bool bandedB = doB && (dtB <= 8);
    int ksb = KsB[cur], vtb = VtB[cur];
    int ksn = KsB[cur ^ 1], vtn = VtB[cur ^ 1];

    // ---- early loads: bias tiles (coalesced), kq when needed, next K/V prefetch ----
    short8 pA0, pA1, pB0, pB1;
    if (bandedA) {
      const u16* tb = bandT + tbaseA + ((size_t)dtA << 12) + t * 16;
      pA0 = *reinterpret_cast<const short8*>(tb);
      pA1 = *reinterpret_cast<const short8*>(tb + 8);
    }
    if (bandedB) {
      const u16* tb = bandT + tbaseB + ((size_t)dtB << 12) + t * 16;
      pB0 = *reinterpret_cast<const short8*>(tb);
      pB1 = *reinterpret_cast<const short8*>(tb + 8);
    }
    float kq[4];
    if (dtA > 8 || (doB && dtB > 8)) {
      #pragma unroll
      for (int c = 0; c < 4; ++c) kq[c] = krq0[bh + k0 + c * 16 + l15];
    }
    short8 nk0, nk1, nv0, nv1;
    if (kt < qtA) {
      const u16* kg = &Kb[(size_t)(b * SEQ + k0 + 64 + vr) * HID + hoff];
      nk0 = *reinterpret_cast<const short8*>(&kg[vc8]);
      nk1 = *reinterpret_cast<const short8*>(&kg[vc8 + 32]);
      const u16* vg = &Vb[(size_t)(b * SEQ + k0 + 64 + vr) * HID + hoff];
      nv0 = *reinterpret_cast<const short8*>(&vg[vc8]);
      nv1 = *reinterpret_cast<const short8*>(&vg[vc8 + 32]);
    }

    // ---- K fragments (shared by A and B) ----
    short8 kb0[4], kb1[4];
    #pragma unroll
    for (int c = 0; c < 4; ++c) {
      kb0[c] = swz8(&smem[ksb], c * 16 + l15, lg);
      kb1[c] = swz8(&smem[ksb], c * 16 + l15, 4 + lg);
    }
    f32x4 sA[4], sB[4];
    __builtin_amdgcn_s_setprio(1);
    #pragma unroll
    for (int c = 0; c < 4; ++c)
      sA[c] = mfma16(aqA1, kb1[c], mfma16(aqA0, kb0[c], Z));
    if (doB) {
      #pragma unroll
      for (int c = 0; c < 4; ++c)
        sB[c] = mfma16(aqB1, kb1[c], mfma16(aqB0, kb0[c], Z));
    }
    __builtin_amdgcn_s_setprio(0);
    // ---- bias (prescaled) + fma-scale + mask ----
    #pragma unroll
    for (int c = 0; c < 4; ++c) {
      #pragma unroll
      for (int r = 0; r < 4; ++r) {
        float bbv = bandedA ? b2f((u16)((c < 2 ? pA0 : pA1)[(c & 1) * 4 + r]))
                            : qb0A[r] + kq[c];
        float v = fmaf(sA[c][r], SM_SCALE, bbv);
        if (dtA == 0) {
          int ql = wv * 16 + lg * 4 + r, kl = c * 16 + l15;
          if (ql < kl) v = -INFINITY;
        }
        sA[c][r] = v;
      }
    }
    if (doB) {
      #pragma unroll
      for (int c = 0; c < 4; ++c) {
        #pragma unroll
        for (int r = 0; r < 4; ++r) {
          float bbv = bandedB ? b2f((u16)((c < 2 ? pB0 : pB1)[(c & 1) * 4 + r]))
                              : qb0B[r] + kq[c];
          float v = fmaf(sB[c][r], SM_SCALE, bbv);
          if (dtB == 0) {
            int ql = wv * 16 + lg * 4 + r, kl = c * 16 + l15;
            if (ql < kl) v = -INFINITY;
          }
          sB[c][r] = v;
        }
      }
    }
    // ---- softmax (DPP row reductions; two independent chains) ----
    float alA[4], alB[4];
    #pragma unroll
    for (int r = 0; r < 4; ++r) {
      float mx = fmaxf(fmaxf(sA[0][r], sA[1][r]), fmaxf(sA[2][r], sA[3][r]));
      mx = rmax16(mx);
      float mn = fmaxf(mA[r], mx);
      alA[r] = __expf(mA[r] - mn);
      float ps = 0.f;
      #pragma unroll
      for (int c = 0; c < 4; ++c) {
        float p = __expf(sA[c][r] - mn);
        sA[c][r] = p;
        ps += p;
      }
      ps = rsum16(ps);
      lA[r] = lA[r] * alA[r] + ps;
      mA[r] = mn;
    }
    if (doB) {
      #pragma unroll
      for (int r = 0; r < 4; ++r) {
        float mx = fmaxf(fmaxf(sB[0][r], sB[1][r]), fmaxf(sB[2][r], sB[3][r]));
        mx = rmax16(mx);
        float mn = fmaxf(mB[r], mx);
        alB[r] = __expf(mB[r] - mn);
        float ps = 0.f;
        #pragma unroll
        for (int c = 0; c < 4; ++c) {
          float p = __expf(sB[c][r] - mn);
          sB[c][r] = p;
          ps += p;
        }
        ps = rsum16(ps);
        lB[r] = lB[r] * alB[r] + ps;
        mB[r] = mn;
      }
    }
    // ---- V fragments (shared) ----
    short8 vb0[4], vb1[4];
    #pragma unroll
    for (int c = 0; c < 4; ++c) {
      int n = c * 16 + l15;
      vb0[c] = *reinterpret_cast<const short8*>(&smem[vtb + vrot(n, lg * 8)]);
      vb1[c] = *reinterpret_cast<const short8*>(&smem[vtb + vrot(n, 32 + lg * 8)]);
    }
    // ---- PV A ----
    #pragma unroll
    for (int c = 0; c < 4; ++c) {
      #pragma unroll
      for (int r = 0; r < 4; ++r) {
        smem[PsO + vrot(wv * 16 + lg * 4 + r, c * 16 + l15)] = f2b(sA[c][r]);
        oA[c][r] *= alA[r];
      }
    }
    int prow = wv * 16 + l15;
    {
      short8 ap0 = *reinterpret_cast<const short8*>(&smem[PsO + vrot(prow, lg * 8)]);
      short8 ap1 = *reinterpret_cast<const short8*>(&smem[PsO + vrot(prow, 32 + lg * 8)]);
      __builtin_amdgcn_s_setprio(1);
      #pragma unroll
      for (int c = 0; c < 4; ++c)
        oA[c] = mfma16(ap1, vb1[c], mfma16(ap0, vb0[c], oA[c]));
      __builtin_amdgcn_s_setprio(0);
    }
    // ---- PV B (same Ps rows reused; same-wave ordering) ----
    if (doB) {
      #pragma unroll
      for (int c = 0; c < 4; ++c) {
        #pragma unroll
        for (int r = 0; r < 4; ++r) {
          smem[PsO + vrot(wv * 16 + lg * 4 + r, c * 16 + l15)] = f2b(sB[c][r]);
          oB[c][r] *= alB[r];
        }
      }
      short8 bp0 = *reinterpret_cast<const short8*>(&smem[PsO + vrot(prow, lg * 8)]);
      short8 bp1 = *reinterpret_cast<const short8*>(&smem[PsO + vrot(prow, 32 + lg * 8)]);
      __builtin_amdgcn_s_setprio(1);
      #pragma unroll
      for (int c = 0; c < 4; ++c)
        oB[c] = mfma16(bp1, vb1[c], mfma16(bp0, vb0[c], oB[c]));
      __builtin_amdgcn_s_setprio(0);
    }
    // ---- write prefetched tile into the other buffer ----
    if (kt < qtA) {
      *reinterpret_cast<short8*>(&smem[ksn + kslot0]) = nk0;
      *reinterpret_cast<short8*>(&smem[ksn + kslot1]) = nk1;
      #pragma unroll
      for (int j = 0; j < 8; ++j) smem[vtn + vslot[j]] = (u16)nv0[j];
      #pragma unroll
      for (int j = 0; j < 8; ++j) smem[vtn + vslot[8 + j]] = (u16)nv1[j];
    }
    __syncthreads(); // single barrier per tile
    cur ^= 1;
  }
  #pragma unroll
  for (int r = 0; r < 4; ++r) { lA[r] = 1.0f / lA[r]; lB[r] = 1.0f / lB[r]; }
  #pragma unroll
  for (int c = 0; c < 4; ++c) {
    #pragma unroll
    for (int r = 0; r < 4; ++r) {
      size_t obA = (size_t)(b * SEQ + qsA + lg * 4 + r) * HID + hoff + c * 16 + l15;
      ATT[obA] = f2b(oA[c][r] * lA[r]);
      size_t obB = (size_t)(b * SEQ + qsB + lg * 4 + r) * HID + hoff + c * 16 + l15;
      ATT[obB] = f2b(oB[c][r] * lB[r]);
    }
  }
}

extern "C" void kernel_launch(void* const* d_in, const int* in_sizes, int n_in,
                              void* d_out, int out_size, void* d_ws, size_t ws_size,
                              hipStream_t stream) {
  const float* x      = (const float*)d_in[0];
  const float* Wq     = (const float*)d_in[1];
  const float* bq     = (const float*)d_in[2];
  const float* Wk     = (const float*)d_in[3];
  const float* bk     = (const float*)d_in[4];
  const float* Wv     = (const float*)d_in[5];
  const float* bv     = (const float*)d_in[6];
  const float* Wo     = (const float*)d_in[7];
  const float* bo     = (const float*)d_in[8];
  const float* relpos = (const float*)d_in[9];
  const float* gamma  = (const float*)d_in[10];
  const float* beta   = (const float*)d_in[11];
  const float* Wrk    = (const float*)d_in[12];
  const float* brk    = (const float*)d_in[13];
  const float* Wrq    = (const float*)d_in[14];
  const float* brq    = (const float*)d_in[15];
  float* out = (float*)d_out;

  u16* wsu = (u16*)d_ws;
  size_t off = 0;
  auto alloc = [&](size_t n) { u16* p = wsu + off; off += n; return p; };
  u16* xb   = alloc(4194304);
  u16* Eb   = alloc(524288);
  u16* WtQ  = alloc(1048576);  // contiguous: WtQ|WtK|WtV for merged QKV GEMM
  u16* WtK  = alloc(1048576);
  u16* WtV  = alloc(1048576);
  u16* WtO  = alloc(1048576);
  u16* WtRK = alloc(1048576);  // contiguous: WtRK|WtRQ for merged rel GEMM
  u16* WtRQ = alloc(1048576);
  u16* Qb2  = alloc(4194304);
  u16* Kb2  = alloc(4194304);
  u16* Vb2  = alloc(4194304);
  u16* ATTb = alloc(4194304);
  u16* RKb2 = alloc(524288);
  u16* RQb2 = alloc(524288);
  float* qrk0 = (float*)(wsu + off); off += 131072;
  float* krq0 = (float*)(wsu + off); off += 131072;
  u16* bandT = alloc((size_t)NB * NH * 32 * 9 * 4096); // 75.5 MB tile-layout bias

  PrepArgs pa;
  pa.tbl = relpos; pa.gamma = gamma; pa.beta = beta; pa.e = Eb;
  pa.x = x; pa.xb = xb;
  pa.ws[0] = Wq; pa.ws[1] = Wk; pa.ws[2] = Wv; pa.ws[3] = Wo; pa.ws[4] = Wrk; pa.ws[5] = Wrq;
  pa.wd[0] = WtQ; pa.wd[1] = WtK; pa.wd[2] = WtV; pa.wd[3] = WtO; pa.wd[4] = WtRK; pa.wd[5] = WtRQ;
  prep_kernel<<<8704, 256, 0, stream>>>(pa);

  GO goQKV = {{bq, bk, bv}, {Qb2, Kb2, Vb2}};
  dim3 gQKV(24, 32); // 768 blocks (%8==0) -> 3 blocks/CU, XCD-chunked
  gemm_bf16<false><<<gQKV, 512, 0, stream>>>(xb, WtQ, goQKV);
  GO goRel = {{brk, brq, brq}, {RKb2, RQb2, RQb2}};
  dim3 gRel2(16, 8); // m64: 128 blocks (%8==0)
  gemm_m64<false><<<gRel2, 256, 0, stream>>>(Eb, WtRK, goRel);

  dim3 gB(32, NH, NB);
  bias_kernel<<<gB, 256, 0, stream>>>(Qb2, Kb2, RKb2, RQb2, bandT, qrk0, krq0);

  dim3 gA(16, NH, NB); // paired q-tiles: 512 balanced blocks
  attn_mfma<<<gA, 256, 0, stream>>>(Qb2, Kb2, Vb2, qrk0, krq0, bandT, ATTb);

  GO goOut = {{bo, bo, bo}, {out, out, out}};
  dim3 gOut(8, 64); // m64: 512 blocks (%8==0) -> 2 blocks/CU
  gemm_m64<true><<<gOut, 256, 0, stream>>>(ATTb, WtO, goOut);
}

// Round 16
// 200.190 us; speedup vs baseline: 1.1464x; 1.0523x over previous
//
#include <hip/hip_runtime.h>
#include <math.h>

#define NH 16
#define HD 64
#define HID 1024
#define SEQ 2048
#define NB 2

typedef __attribute__((ext_vector_type(8))) short short8;
typedef __attribute__((ext_vector_type(4))) float f32x4;
typedef unsigned short u16;
typedef unsigned int u32;

constexpr float LN_EPS_C = 1e-5f;
constexpr float SM_SCALE = 0.07216878364870323f;              // 1/sqrt(64*3)
constexpr float SM_SCALE2 = 0.07216878364870323f * 1.4426950408889634f; // *log2(e): exp2 domain

__device__ inline u16 f2b(float f) {
  unsigned u = __builtin_bit_cast(unsigned, f);
  u = (u + 0x7FFFu + ((u >> 16) & 1u)) >> 16;
  return (u16)u;
}
__device__ inline float b2f(u16 h) {
  unsigned u = ((unsigned)h) << 16;
  return __builtin_bit_cast(float, u);
}
__device__ inline u32 pk2(float lo, float hi) {
  return (u32)f2b(lo) | ((u32)f2b(hi) << 16);
}
__device__ inline f32x4 mfma16(short8 a, short8 b, f32x4 c) {
  return __builtin_amdgcn_mfma_f32_16x16x32_bf16(a, b, c, 0, 0, 0);
}
// 2^x via the native transcendental (logits are pre-scaled by log2e)
__device__ inline float ex2(float x) {
  float r;
  asm("v_exp_f32 %0, %1" : "=v"(r) : "v"(x));
  return r;
}
// swizzled read of a [rows][64] bf16 tile whose writes used slot = chunk^(row&7)
__device__ inline short8 swz8(const u16* base, int row, int hc) {
  return *reinterpret_cast<const short8*>(&base[row * 64 + 8 * (hc ^ (row & 7))]);
}
// add-rotate swizzle for [64 row][72-stride] tiles, col in [0,64).
__device__ inline int vrot(int row, int col) {
  return row * 72 + ((col + 16 * ((row >> 3) & 3)) & 63);
}
// DPP row-rotate reduction within the 16-lane row group
template <int N>
__device__ inline float rorf(float x) {
  return __builtin_bit_cast(float,
      __builtin_amdgcn_update_dpp(0, __builtin_bit_cast(int, x),
                                  0x120 + N, 0xF, 0xF, true));
}
__device__ inline float rmax16(float x) {
  x = fmaxf(x, rorf<1>(x)); x = fmaxf(x, rorf<2>(x));
  x = fmaxf(x, rorf<4>(x)); x = fmaxf(x, rorf<8>(x));
  return x;
}
__device__ inline float rsum16(float x) {
  x += rorf<1>(x); x += rorf<2>(x); x += rorf<4>(x); x += rorf<8>(x);
  return x;
}

// ---------------- fused preprocessing: ln | f32->bf16 conv | 6x weight transpose ----------------
struct PrepArgs {
  const float* tbl; const float* gamma; const float* beta; u16* e;
  const float* x; u16* xb;
  const float* ws[6]; u16* wd[6];
};
__global__ __launch_bounds__(256) void prep_kernel(PrepArgs p) {
  __shared__ float T[32][33];
  __shared__ float sb[4], ssb[4];
  int bid = blockIdx.x;
  int t = threadIdx.x;
  if (bid < 512) {
    int row = bid;
    const float4* rp = reinterpret_cast<const float4*>(p.tbl + (size_t)row * HID);
    float4 x = rp[t];
    float s = x.x + x.y + x.z + x.w;
    float ss = x.x * x.x + x.y * x.y + x.z * x.z + x.w * x.w;
    #pragma unroll
    for (int o = 1; o < 64; o <<= 1) {
      s += __shfl_xor(s, o);
      ss += __shfl_xor(ss, o);
    }
    int w = t >> 6;
    if ((t & 63) == 0) { sb[w] = s; ssb[w] = ss; }
    __syncthreads();
    s = sb[0] + sb[1] + sb[2] + sb[3];
    ss = ssb[0] + ssb[1] + ssb[2] + ssb[3];
    float mu = s * (1.0f / HID);
    float var = ss * (1.0f / HID) - mu * mu;
    float rs = rsqrtf(var + LN_EPS_C);
    float4 g = reinterpret_cast<const float4*>(p.gamma)[t];
    float4 bt = reinterpret_cast<const float4*>(p.beta)[t];
    ushort4 o4;
    o4.x = f2b((x.x - mu) * rs * g.x + bt.x);
    o4.y = f2b((x.y - mu) * rs * g.y + bt.y);
    o4.z = f2b((x.z - mu) * rs * g.z + bt.z);
    o4.w = f2b((x.w - mu) * rs * g.w + bt.w);
    *reinterpret_cast<ushort4*>(&p.e[(size_t)row * HID + t * 4]) = o4;
  } else if (bid < 2560) {
    int i = ((bid - 512) * 256 + t) * 8;
    float4 a = *reinterpret_cast<const float4*>(&p.x[i]);
    float4 c = *reinterpret_cast<const float4*>(&p.x[i + 4]);
    short8 o;
    o[0] = (short)f2b(a.x); o[1] = (short)f2b(a.y); o[2] = (short)f2b(a.z); o[3] = (short)f2b(a.w);
    o[4] = (short)f2b(c.x); o[5] = (short)f2b(c.y); o[6] = (short)f2b(c.z); o[7] = (short)f2b(c.w);
    *reinterpret_cast<short8*>(&p.xb[i]) = o;
  } else {
    int z = (bid - 2560) >> 10;
    int rem = (bid - 2560) & 1023;
    int bn = (rem & 31) * 32, bk = (rem >> 5) * 32;
    const float* W = p.ws[z];
    u16* Wt = p.wd[z];
    int r = t >> 3, c4 = (t & 7) * 4;
    float4 v = *reinterpret_cast<const float4*>(&W[(size_t)(bk + r) * HID + bn + c4]);
    T[r][c4 + 0] = v.x; T[r][c4 + 1] = v.y; T[r][c4 + 2] = v.z; T[r][c4 + 3] = v.w;
    __syncthreads();
    int n = t >> 3, k4 = (t & 7) * 4;
    ushort4 o;
    o.x = f2b(T[k4 + 0][n]); o.y = f2b(T[k4 + 1][n]);
    o.z = f2b(T[k4 + 2][n]); o.w = f2b(T[k4 + 3][n]);
    *reinterpret_cast<ushort4*>(&Wt[(size_t)(bn + n) * HID + bk + k4]) = o;
  }
}

// ---------------- fused QKV + rel GEMM: 512 threads, 128x128, BK=64, flat XCD swizzle ----------------
// 832 blocks: lin<768 -> C = xb @ WtQKV (M=4096, N=3072); else -> C = Eb @ WtRel (M=512, N=2048).
struct G5 {
  const float* bias[5];
  u16* out[5];
};
__global__ __launch_bounds__(512) void gemm_qkvrel(const u16* __restrict__ xb,
    const u16* __restrict__ WtQKV, const u16* __restrict__ Eb,
    const u16* __restrict__ WtRel, G5 g5) {
  __shared__ u16 Al[8192]; // [128][64] swizzled
  __shared__ u16 Bl[8192];
  int t = threadIdx.x;
  int raw = blockIdx.x;
  int lin = (raw & 7) * 104 + (raw >> 3); // bijective (832 = 8*104)
  const u16 *A, *Bt;
  const float* bias;
  u16* Cout;
  int rb, cb;
  if (lin < 768) {
    cb = (lin % 24) * 128; rb = (lin / 24) * 128;
    A = xb; Bt = WtQKV;
    bias = g5.bias[cb >> 10]; Cout = g5.out[cb >> 10];
  } else {
    int j = lin - 768;
    cb = (j & 15) * 128; rb = (j >> 4) * 128;
    A = Eb; Bt = WtRel;
    bias = g5.bias[3 + (cb >> 10)]; Cout = g5.out[3 + (cb >> 10)];
  }
  int cbl = cb & 1023;
  int wv = t >> 6, lane = t & 63, l15 = lane & 15, lg = lane >> 4;
  int wr = (wv >> 2) * 64, wc = (wv & 3) * 32;
  int srow = t >> 2, sch = t & 3;
  f32x4 acc[4][2];
  #pragma unroll
  for (int i = 0; i < 4; ++i)
    #pragma unroll
    for (int j = 0; j < 2; ++j) acc[i][j] = (f32x4){0.f, 0.f, 0.f, 0.f};
  const u16* Ap = A + (size_t)(rb + srow) * HID;
  const u16* Bp = Bt + (size_t)(cb + srow) * HID;
  int slot0 = 8 * (sch ^ (srow & 7));
  int slot1 = 8 * ((sch + 4) ^ (srow & 7));
  short8 pa0 = *reinterpret_cast<const short8*>(&Ap[sch * 8]);
  short8 pa1 = *reinterpret_cast<const short8*>(&Ap[(sch + 4) * 8]);
  short8 pb0 = *reinterpret_cast<const short8*>(&Bp[sch * 8]);
  short8 pb1 = *reinterpret_cast<const short8*>(&Bp[(sch + 4) * 8]);
  for (int kk = 0; kk < HID; kk += 64) {
    __syncthreads();
    *reinterpret_cast<short8*>(&Al[srow * 64 + slot0]) = pa0;
    *reinterpret_cast<short8*>(&Al[srow * 64 + slot1]) = pa1;
    *reinterpret_cast<short8*>(&Bl[srow * 64 + slot0]) = pb0;
    *reinterpret_cast<short8*>(&Bl[srow * 64 + slot1]) = pb1;
    __syncthreads();
    if (kk + 64 < HID) {
      pa0 = *reinterpret_cast<const short8*>(&Ap[kk + 64 + sch * 8]);
      pa1 = *reinterpret_cast<const short8*>(&Ap[kk + 64 + (sch + 4) * 8]);
      pb0 = *reinterpret_cast<const short8*>(&Bp[kk + 64 + sch * 8]);
      pb1 = *reinterpret_cast<const short8*>(&Bp[kk + 64 + (sch + 4) * 8]);
    }
    #pragma unroll
    for (int s = 0; s < 2; ++s) {
      short8 am[4], bn[2];
      #pragma unroll
      for (int i = 0; i < 4; ++i) am[i] = swz8(Al, wr + i * 16 + l15, s * 4 + lg);
      #pragma unroll
      for (int j = 0; j < 2; ++j) bn[j] = swz8(Bl, wc + j * 16 + l15, s * 4 + lg);
      #pragma unroll
      for (int i = 0; i < 4; ++i)
        #pragma unroll
        for (int j = 0; j < 2; ++j)
          acc[i][j] = mfma16(am[i], bn[j], acc[i][j]);
    }
  }
  #pragma unroll
  for (int j = 0; j < 2; ++j) {
    float bv = bias[cbl + wc + j * 16 + l15];
    #pragma unroll
    for (int i = 0; i < 4; ++i) {
      #pragma unroll
      for (int r = 0; r < 4; ++r) {
        size_t idx = (size_t)(rb + wr + i * 16 + lg * 4 + r) * HID + cbl + wc + j * 16 + l15;
        Cout[idx] = f2b(acc[i][j][r] + bv);
      }
    }
  }
}

// ---------------- bf16 MFMA GEMM: 256 threads, 64x128 tile, XCD swizzle (output GEMM) ----------------
struct GO {
  const float* bias;
  float* out;
};
__global__ __launch_bounds__(256) void gemm_m64(const u16* __restrict__ A,
    const u16* __restrict__ Bt, GO go) {
  __shared__ u16 Al[4096]; // [64][64] swizzled
  __shared__ u16 Bl[8192]; // [128][64] swizzled
  int t = threadIdx.x;
  int gx = gridDim.x;
  int nwg = gx * gridDim.y;
  int lin = blockIdx.y * gx + blockIdx.x;
  lin = (lin & 7) * (nwg >> 3) + (lin >> 3); // bijective (nwg % 8 == 0)
  int cb = (lin % gx) * 128, rb = (lin / gx) * 64;
  const float* bias = go.bias;
  float* Cout = go.out;
  int wv = t >> 6, lane = t & 63, l15 = lane & 15, lg = lane >> 4;
  int wc = wv * 32;
  int arow = t >> 2, ach = t & 3;
  int aslot0 = 8 * (ach ^ (arow & 7));
  int aslot1 = 8 * ((ach + 4) ^ (arow & 7));
  int brow = t >> 1, bch = (t & 1) * 4;
  const u16* Ap = A + (size_t)(rb + arow) * HID;
  const u16* Bp = Bt + (size_t)(cb + brow) * HID;
  f32x4 acc[4][2];
  #pragma unroll
  for (int i = 0; i < 4; ++i)
    #pragma unroll
    for (int j = 0; j < 2; ++j) acc[i][j] = (f32x4){0.f, 0.f, 0.f, 0.f};
  short8 pa0 = *reinterpret_cast<const short8*>(&Ap[ach * 8]);
  short8 pa1 = *reinterpret_cast<const short8*>(&Ap[(ach + 4) * 8]);
  short8 pb[4];
  #pragma unroll
  for (int j = 0; j < 4; ++j)
    pb[j] = *reinterpret_cast<const short8*>(&Bp[(bch + j) * 8]);
  for (int kk = 0; kk < HID; kk += 64) {
    __syncthreads();
    *reinterpret_cast<short8*>(&Al[arow * 64 + aslot0]) = pa0;
    *reinterpret_cast<short8*>(&Al[arow * 64 + aslot1]) = pa1;
    #pragma unroll
    for (int j = 0; j < 4; ++j)
      *reinterpret_cast<short8*>(&Bl[brow * 64 + 8 * ((bch + j) ^ (brow & 7))]) = pb[j];
    __syncthreads();
    if (kk + 64 < HID) {
      pa0 = *reinterpret_cast<const short8*>(&Ap[kk + 64 + ach * 8]);
      pa1 = *reinterpret_cast<const short8*>(&Ap[kk + 64 + (ach + 4) * 8]);
      #pragma unroll
      for (int j = 0; j < 4; ++j)
        pb[j] = *reinterpret_cast<const short8*>(&Bp[kk + 64 + (bch + j) * 8]);
    }
    #pragma unroll
    for (int s = 0; s < 2; ++s) {
      short8 am[4], bn[2];
      #pragma unroll
      for (int i = 0; i < 4; ++i) am[i] = swz8(Al, i * 16 + l15, s * 4 + lg);
      #pragma unroll
      for (int j = 0; j < 2; ++j) bn[j] = swz8(Bl, wc + j * 16 + l15, s * 4 + lg);
      #pragma unroll
      for (int i = 0; i < 4; ++i)
        #pragma unroll
        for (int j = 0; j < 2; ++j)
          acc[i][j] = mfma16(am[i], bn[j], acc[i][j]);
    }
  }
  #pragma unroll
  for (int j = 0; j < 2; ++j) {
    float bv = bias[cb + wc + j * 16 + l15];
    #pragma unroll
    for (int i = 0; i < 4; ++i) {
      #pragma unroll
      for (int r = 0; r < 4; ++r) {
        size_t idx = (size_t)(rb + i * 16 + lg * 4 + r) * HID + cb + wc + j * 16 + l15;
        Cout[idx] = acc[i][j][r] + bv;
      }
    }
  }
}

// ---------------- band bias + rank-1 dots (fused), per-tile thread-ordered, PRESCALED (exp2 dom) ----------------
__global__ __launch_bounds__(256, 3) void bias_kernel(
    const u16* __restrict__ Qb, const u16* __restrict__ Kb,
    const u16* __restrict__ RKb, const u16* __restrict__ RQb,
    u16* __restrict__ bandT, float* __restrict__ qrk0,
    float* __restrict__ krq0) {
  __shared__ u16 smem[20992]; // 41984 B -> 3 blocks/CU
  const int KsO = 0, UO = 4096;
  const int RKO = UO, RQO = UO + 8192;
  const int G1O = UO, G2O = UO + 8448;

  int qt = blockIdx.x;
  int h = blockIdx.y, b = blockIdx.z;
  int q0 = qt * 64;
  int t = threadIdx.x;
  int wv = t >> 6, lane = t & 63, l15 = lane & 15, lg = lane >> 4;
  int qs = q0 + wv * 16;
  int hoff = h * HD;
  int bh = (b * NH + h) * SEQ;

  // ---- fused rank-1 bias for this block's 64 q-rows ----
  {
    int i = q0 + (t >> 2);
    int sub = t & 3;
    size_t rbase = (size_t)(b * SEQ + i) * HID + hoff + sub * 16;
    size_t tb2 = (size_t)hoff + sub * 16;
    float s1 = 0.f, s2 = 0.f;
    #pragma unroll
    for (int c = 0; c < 2; ++c) {
      short8 qv = *reinterpret_cast<const short8*>(&Qb[rbase + c * 8]);
      short8 rv = *reinterpret_cast<const short8*>(&RKb[tb2 + c * 8]);
      short8 kv = *reinterpret_cast<const short8*>(&Kb[rbase + c * 8]);
      short8 uv = *reinterpret_cast<const short8*>(&RQb[tb2 + c * 8]);
      #pragma unroll
      for (int j = 0; j < 8; ++j) {
        s1 += b2f((u16)qv[j]) * b2f((u16)rv[j]);
        s2 += b2f((u16)kv[j]) * b2f((u16)uv[j]);
      }
    }
    s1 += __shfl_xor(s1, 1); s1 += __shfl_xor(s1, 2);
    s2 += __shfl_xor(s2, 1); s2 += __shfl_xor(s2, 2);
    if (sub == 0) { qrk0[bh + i] = s1 * SM_SCALE2; krq0[bh + i] = s2 * SM_SCALE2; }
  }

  size_t qgrow = (size_t)(b * SEQ + qs + l15) * HID + hoff;
  short8 aq0 = *reinterpret_cast<const short8*>(&Qb[qgrow + lg * 8]);
  short8 aq1 = *reinterpret_cast<const short8*>(&Qb[qgrow + 32 + lg * 8]);

  const f32x4 Z = (f32x4){0.f, 0.f, 0.f, 0.f};
  int vr = t >> 2, vc8 = (t & 3) * 8;
  int ktlo = qt - 8; if (ktlo < 0) ktlo = 0;
  size_t tbase = (((size_t)(b * NH + h) * 32 + qt) * 9) << 12;

  for (int kt = ktlo; kt <= qt; ++kt) {
    int k0 = kt * 64;
    int dt = qt - kt;
    int wlo = 448 - 64 * dt; if (wlo < 0) wlo = 0;
    __syncthreads(); // #1: previous iteration's gathers done
    {
      const u16* kg = &Kb[(size_t)(b * SEQ + k0 + vr) * HID + hoff];
      int c0 = vc8 >> 3;
      *reinterpret_cast<short8*>(&smem[KsO + vr * 64 + 8 * (c0 ^ (vr & 7))]) =
          *reinterpret_cast<const short8*>(&kg[vc8]);
      *reinterpret_cast<short8*>(&smem[KsO + vr * 64 + 8 * ((c0 + 4) ^ (vr & 7))]) =
          *reinterpret_cast<const short8*>(&kg[vc8 + 32]);
    }
    for (int e2 = t; e2 < 1024; e2 += 256) {
      int rr = e2 >> 3, cch = e2 & 7;
      int wr2 = wlo + rr; if (wr2 > 511) wr2 = 511;
      size_t gb = (size_t)wr2 * HID + hoff + cch * 8;
      int slot = 8 * (cch ^ (rr & 7));
      *reinterpret_cast<short8*>(&smem[RKO + rr * 64 + slot]) =
          *reinterpret_cast<const short8*>(&RKb[gb]);
      *reinterpret_cast<short8*>(&smem[RQO + rr * 64 + slot]) =
          *reinterpret_cast<const short8*>(&RQb[gb]);
    }
    __syncthreads(); // #2: staging visible
    u32 g1p[16], g2p[16];
    #pragma unroll
    for (int cw = 0; cw < 8; ++cw) {
      short8 r0 = swz8(&smem[RKO], cw * 16 + l15, lg);
      short8 r1 = swz8(&smem[RKO], cw * 16 + l15, 4 + lg);
      f32x4 g = mfma16(r1, aq1, mfma16(r0, aq0, Z));
      g1p[2 * cw] = pk2(g[0], g[1]);
      g1p[2 * cw + 1] = pk2(g[2], g[3]);
    }
    short8 kw0 = swz8(&smem[KsO], wv * 16 + l15, lg);
    short8 kw1 = swz8(&smem[KsO], wv * 16 + l15, 4 + lg);
    #pragma unroll
    for (int cw = 0; cw < 8; ++cw) {
      short8 u0 = swz8(&smem[RQO], cw * 16 + l15, lg);
      short8 u1 = swz8(&smem[RQO], cw * 16 + l15, 4 + lg);
      f32x4 g = mfma16(u1, kw1, mfma16(u0, kw0, Z));
      g2p[2 * cw] = pk2(g[0], g[1]);
      g2p[2 * cw + 1] = pk2(g[2], g[3]);
    }
    __syncthreads(); // #3: band reads done; U reusable for G
    #pragma unroll
    for (int cw = 0; cw < 8; ++cw) {
      *reinterpret_cast<uint2*>(&smem[G1O + (wv * 16 + l15) * 132 + cw * 16 + lg * 4]) =
          make_uint2(g1p[2 * cw], g1p[2 * cw + 1]);
      *reinterpret_cast<uint2*>(&smem[G2O + (wv * 16 + l15) * 132 + cw * 16 + lg * 4]) =
          make_uint2(g2p[2 * cw], g2p[2 * cw + 1]);
    }
    __syncthreads(); // #4: G visible
    u16* outp = bandT + tbase + ((size_t)dt << 12) + t * 16;
    #pragma unroll
    for (int c = 0; c < 4; ++c) {
      float vv[4];
      #pragma unroll
      for (int r = 0; r < 4; ++r) {
        int q = qs + lg * 4 + r;
        int k = k0 + c * 16 + l15;
        int wi = 511 - (q - k) - wlo; if (wi < 0) wi = 0;
        vv[r] = (b2f(smem[G1O + (wv * 16 + lg * 4 + r) * 132 + wi]) +
                 b2f(smem[G2O + (c * 16 + l15) * 132 + wi])) * SM_SCALE2;
      }
      *reinterpret_cast<uint2*>(outp + c * 4) =
          make_uint2(pk2(vv[0], vv[1]), pk2(vv[2], vv[3]));
    }
  }
}

// ---------------- fused DeBERTa flash attention: paired q-tiles, exp2 softmax, XCD-chunked ----------------
__global__ __launch_bounds__(256, 2) void attn_mfma(
    const u16* __restrict__ Qb, const u16* __restrict__ Kb,
    const u16* __restrict__ Vb, const float* __restrict__ qrk0,
    const float* __restrict__ krq0, const u16* __restrict__ bandT,
    u16* __restrict__ ATT) {
  __shared__ u16 smem[22016];
  const int KsB[2] = {0, 4096};
  const int VtB[2] = {8192, 12800};
  const int PsO = 17408;

  // XCD-chunked bijective remap: blocks sharing (b,h)'s K/V stream stay on one XCD L2
  int flat = (int)blockIdx.x + 16 * ((int)blockIdx.y + 16 * (int)blockIdx.z);
  flat = (flat & 7) * 64 + (flat >> 3); // 512 = 8 * 64
  int pairi = flat & 15;
  int h = (flat >> 4) & 15;
  int b = flat >> 8;
  int qtA = 31 - pairi; // heavy stream
  int qtB = pairi;      // light stream (prefix of A's k-range)
  int t = threadIdx.x;
  int wv = t >> 6, lane = t & 63, l15 = lane & 15, lg = lane >> 4;
  int hoff = h * HD;
  int bh = (b * NH + h) * SEQ;
  size_t tbaseA = (((size_t)(b * NH + h) * 32 + qtA) * 9) << 12;
  size_t tbaseB = (((size_t)(b * NH + h) * 32 + qtB) * 9) << 12;

  int qsA = qtA * 64 + wv * 16;
  int qsB = qtB * 64 + wv * 16;
  size_t qgA = (size_t)(b * SEQ + qsA + l15) * HID + hoff;
  size_t qgB = (size_t)(b * SEQ + qsB + l15) * HID + hoff;
  short8 aqA0 = *reinterpret_cast<const short8*>(&Qb[qgA + lg * 8]);
  short8 aqA1 = *reinterpret_cast<const short8*>(&Qb[qgA + 32 + lg * 8]);
  short8 aqB0 = *reinterpret_cast<const short8*>(&Qb[qgB + lg * 8]);
  short8 aqB1 = *reinterpret_cast<const short8*>(&Qb[qgB + 32 + lg * 8]);
  float qb0A[4], qb0B[4];
  #pragma unroll
  for (int r = 0; r < 4; ++r) {
    qb0A[r] = qrk0[bh + qsA + lg * 4 + r];
    qb0B[r] = qrk0[bh + qsB + lg * 4 + r];
  }

  float mA[4], lA[4], mB[4], lB[4];
  f32x4 oA[4], oB[4];
  #pragma unroll
  for (int r = 0; r < 4; ++r) { mA[r] = -INFINITY; lA[r] = 0.f; mB[r] = -INFINITY; lB[r] = 0.f; }
  #pragma unroll
  for (int c = 0; c < 4; ++c) {
    oA[c] = (f32x4){0.f, 0.f, 0.f, 0.f};
    oB[c] = (f32x4){0.f, 0.f, 0.f, 0.f};
  }

  const f32x4 Z = (f32x4){0.f, 0.f, 0.f, 0.f};
  int vr = t >> 2, vc8 = (t & 3) * 8;
  int c0s = vc8 >> 3;
  int kslot0 = vr * 64 + 8 * (c0s ^ (vr & 7));
  int kslot1 = vr * 64 + 8 * ((c0s + 4) ^ (vr & 7));
  int vslot[16];
  #pragma unroll
  for (int j = 0; j < 8; ++j) {
    vslot[j] = vrot(vc8 + j, vr);
    vslot[8 + j] = vrot(vc8 + 32 + j, vr);
  }

  // ---- prologue: stage tile 0 into buffer 0 ----
  {
    const u16* kg = &Kb[(size_t)(b * SEQ + vr) * HID + hoff];
    short8 k0v = *reinterpret_cast<const short8*>(&kg[vc8]);
    short8 k1v = *reinterpret_cast<const short8*>(&kg[vc8 + 32]);
    *reinterpret_cast<short8*>(&smem[KsB[0] + kslot0]) = k0v;
    *reinterpret_cast<short8*>(&smem[KsB[0] + kslot1]) = k1v;
    const u16* vg = &Vb[(size_t)(b * SEQ + vr) * HID + hoff];
    short8 v0v = *reinterpret_cast<const short8*>(&vg[vc8]);
    short8 v1v = *reinterpret_cast<const short8*>(&vg[vc8 + 32]);
    #pragma unroll
    for (int j = 0; j < 8; ++j) smem[VtB[0] + vslot[j]] = (u16)v0v[j];
    #pragma unroll
    for (int j = 0; j < 8; ++j) smem[VtB[0] + vslot[8 + j]] = (u16)v1v[j];
  }
  __syncthreads();

  int cur = 0;
  for (int kt = 0; kt <= qtA; ++kt) {
    int k0 = kt * 64;
    int dtA = qtA - kt;
    bool doB = (kt <= qtB);
    int dtB = qtB - kt;
    bool bandedA = (dtA <= 8);
    bool bandedB = doB && (dtB <= 8);
    int ksb = KsB[cur], vtb = VtB[cur];
    int ksn = KsB[cur ^ 1], vtn = VtB[cur ^ 1];

    // ---- early loads: bias tiles (coalesced), kq when needed, next K/V prefetch ----
    short8 pA0, pA1, pB0, pB1;
    if (bandedA) {
      const u16* tb = bandT + tbaseA + ((size_t)dtA << 12) + t * 16;
      pA0 = *reinterpret_cast<const short8*>(tb);
      pA1 = *reinterpret_cast<const short8*>(tb + 8);
    }
    if (bandedB) {
      const u16* tb = bandT + tbaseB + ((size_t)dtB << 12) + t * 16;
      pB0 = *reinterpret_cast<const short8*>(tb);
      pB1 = *reinterpret_cast<const short8*>(tb + 8);
    }
    float kq[4];
    if (dtA > 8 || (doB && dtB > 8)) {
      #pragma unroll
      for (int c = 0; c < 4; ++c) kq[c] = krq0[bh + k0 + c * 16 + l15];
    }
    short8 nk0, nk1, nv0, nv1;
    if (kt < qtA) {
      const u16* kg = &Kb[(size_t)(b * SEQ + k0 + 64 + vr) * HID + hoff];
      nk0 = *reinterpret_cast<const short8*>(&kg[vc8]);
      nk1 = *reinterpret_cast<const short8*>(&kg[vc8 + 32]);
      const u16* vg = &Vb[(size_t)(b * SEQ + k0 + 64 + vr) * HID + hoff];
      nv0 = *reinterpret_cast<const short8*>(&vg[vc8]);
      nv1 = *reinterpret_cast<const short8*>(&vg[vc8 + 32]);
    }

    // ---- K fragments (shared by A and B) ----
    short8 kb0[4], kb1[4];
    #pragma unroll
    for (int c = 0; c < 4; ++c) {
      kb0[c] = swz8(&smem[ksb], c * 16 + l15, lg);
      kb1[c] = swz8(&smem[ksb], c * 16 + l15, 4 + lg);
    }
    f32x4 sA[4], sB[4];
    __builtin_amdgcn_s_setprio(1);
    #pragma unroll
    for (int c = 0; c < 4; ++c)
      sA[c] = mfma16(aqA1, kb1[c], mfma16(aqA0, kb0[c], Z));
    if (doB) {
      #pragma unroll
      for (int c = 0; c < 4; ++c)
        sB[c] = mfma16(aqB1, kb1[c], mfma16(aqB0, kb0[c], Z));
    }
    __builtin_amdgcn_s_setprio(0);
    // ---- bias (prescaled, exp2 domain) + fma-scale + mask ----
    #pragma unroll
    for (int c = 0; c < 4; ++c) {
      #pragma unroll
      for (int r = 0; r < 4; ++r) {
        float bbv = bandedA ? b2f((u16)((c < 2 ? pA0 : pA1)[(c & 1) * 4 + r]))
                            : qb0A[r] + kq[c];
        float v = fmaf(sA[c][r], SM_SCALE2, bbv);
        if (dtA == 0) {
          int ql = wv * 16 + lg * 4 + r, kl = c * 16 + l15;
          if (ql < kl) v = -INFINITY;
        }
        sA[c][r] = v;
      }
    }
    if (doB) {
      #pragma unroll
      for (int c = 0; c < 4; ++c) {
        #pragma unroll
        for (int r = 0; r < 4; ++r) {
          float bbv = bandedB ? b2f((u16)((c < 2 ? pB0 : pB1)[(c & 1) * 4 + r]))
                              : qb0B[r] + kq[c];
          float v = fmaf(sB[c][r], SM_SCALE2, bbv);
          if (dtB == 0) {
            int ql = wv * 16 + lg * 4 + r, kl = c * 16 + l15;
            if (ql < kl) v = -INFINITY;
          }
          sB[c][r] = v;
        }
      }
    }
    // ---- softmax (DPP row reductions; exp2; two independent chains) ----
    float alA[4], alB[4];
    #pragma unroll
    for (int r = 0; r < 4; ++r) {
      float mx = fmaxf(fmaxf(sA[0][r], sA[1][r]), fmaxf(sA[2][r], sA[3][r]));
      mx = rmax16(mx);
      float mn = fmaxf(mA[r], mx);
      alA[r] = ex2(mA[r] - mn);
      float ps = 0.f;
      #pragma unroll
      for (int c = 0; c < 4; ++c) {
        float p = ex2(sA[c][r] - mn);
        sA[c][r] = p;
        ps += p;
      }
      ps = rsum16(ps);
      lA[r] = lA[r] * alA[r] + ps;
      mA[r] = mn;
    }
    if (doB) {
      #pragma unroll
      for (int r = 0; r < 4; ++r) {
        float mx = fmaxf(fmaxf(sB[0][r], sB[1][r]), fmaxf(sB[2][r], sB[3][r]));
        mx = rmax16(mx);
        float mn = fmaxf(mB[r], mx);
        alB[r] = ex2(mB[r] - mn);
        float ps = 0.f;
        #pragma unroll
        for (int c = 0; c < 4; ++c) {
          float p = ex2(sB[c][r] - mn);
          sB[c][r] = p;
          ps += p;
        }
        ps = rsum16(ps);
        lB[r] = lB[r] * alB[r] + ps;
        mB[r] = mn;
      }
    }
    // ---- V fragments (shared) ----
    short8 vb0[4], vb1[4];
    #pragma unroll
    for (int c = 0; c < 4; ++c) {
      int n = c * 16 + l15;
      vb0[c] = *reinterpret_cast<const short8*>(&smem[vtb + vrot(n, lg * 8)]);
      vb1[c] = *reinterpret_cast<const short8*>(&smem[vtb + vrot(n, 32 + lg * 8)]);
    }
    // ---- PV A ----
    #pragma unroll
    for (int c = 0; c < 4; ++c) {
      #pragma unroll
      for (int r = 0; r < 4; ++r) {
        smem[PsO + vrot(wv * 16 + lg * 4 + r, c * 16 + l15)] = f2b(sA[c][r]);
        oA[c][r] *= alA[r];
      }
    }
    int prow = wv * 16 + l15;
    {
      short8 ap0 = *reinterpret_cast<const short8*>(&smem[PsO + vrot(prow, lg * 8)]);
      short8 ap1 = *reinterpret_cast<const short8*>(&smem[PsO + vrot(prow, 32 + lg * 8)]);
      __builtin_amdgcn_s_setprio(1);
      #pragma unroll
      for (int c = 0; c < 4; ++c)
        oA[c] = mfma16(ap1, vb1[c], mfma16(ap0, vb0[c], oA[c]));
      __builtin_amdgcn_s_setprio(0);
    }
    // ---- PV B (same Ps rows reused; same-wave ordering) ----
    if (doB) {
      #pragma unroll
      for (int c = 0; c < 4; ++c) {
        #pragma unroll
        for (int r = 0; r < 4; ++r) {
          smem[PsO + vrot(wv * 16 + lg * 4 + r, c * 16 + l15)] = f2b(sB[c][r]);
          oB[c][r] *= alB[r];
        }
      }
      short8 bp0 = *reinterpret_cast<const short8*>(&smem[PsO + vrot(prow, lg * 8)]);
      short8 bp1 = *reinterpret_cast<const short8*>(&smem[PsO + vrot(prow, 32 + lg * 8)]);
      __builtin_amdgcn_s_setprio(1);
      #pragma unroll
      for (int c = 0; c < 4; ++c)
        oB[c] = mfma16(bp1, vb1[c], mfma16(bp0, vb0[c], oB[c]));
      __builtin_amdgcn_s_setprio(0);
    }
    // ---- write prefetched tile into the other buffer ----
    if (kt < qtA) {
      *reinterpret_cast<short8*>(&smem[ksn + kslot0]) = nk0;
      *reinterpret_cast<short8*>(&smem[ksn + kslot1]) = nk1;
      #pragma unroll
      for (int j = 0; j < 8; ++j) smem[vtn + vslot[j]] = (u16)nv0[j];
      #pragma unroll
      for (int j = 0; j < 8; ++j) smem[vtn + vslot[8 + j]] = (u16)nv1[j];
    }
    __syncthreads(); // single barrier per tile
    cur ^= 1;
  }
  #pragma unroll
  for (int r = 0; r < 4; ++r) { lA[r] = 1.0f / lA[r]; lB[r] = 1.0f / lB[r]; }
  #pragma unroll
  for (int c = 0; c < 4; ++c) {
    #pragma unroll
    for (int r = 0; r < 4; ++r) {
      size_t obA = (size_t)(b * SEQ + qsA + lg * 4 + r) * HID + hoff + c * 16 + l15;
      ATT[obA] = f2b(oA[c][r] * lA[r]);
      size_t obB = (size_t)(b * SEQ + qsB + lg * 4 + r) * HID + hoff + c * 16 + l15;
      ATT[obB] = f2b(oB[c][r] * lB[r]);
    }
  }
}

extern "C" void kernel_launch(void* const* d_in, const int* in_sizes, int n_in,
                              void* d_out, int out_size, void* d_ws, size_t ws_size,
                              hipStream_t stream) {
  const float* x      = (const float*)d_in[0];
  const float* Wq     = (const float*)d_in[1];
  const float* bq     = (const float*)d_in[2];
  const float* Wk     = (const float*)d_in[3];
  const float* bk     = (const float*)d_in[4];
  const float* Wv     = (const float*)d_in[5];
  const float* bv     = (const float*)d_in[6];
  const float* Wo     = (const float*)d_in[7];
  const float* bo     = (const float*)d_in[8];
  const float* relpos = (const float*)d_in[9];
  const float* gamma  = (const float*)d_in[10];
  const float* beta   = (const float*)d_in[11];
  const float* Wrk    = (const float*)d_in[12];
  const float* brk    = (const float*)d_in[13];
  const float* Wrq    = (const float*)d_in[14];
  const float* brq    = (const float*)d_in[15];
  float* out = (float*)d_out;

  u16* wsu = (u16*)d_ws;
  size_t off = 0;
  auto alloc = [&](size_t n) { u16* p = wsu + off; off += n; return p; };
  u16* xb   = alloc(4194304);
  u16* Eb   = alloc(524288);
  u16* WtQ  = alloc(1048576);  // contiguous: WtQ|WtK|WtV for merged QKV GEMM
  u16* WtK  = alloc(1048576);
  u16* WtV  = alloc(1048576);
  u16* WtO  = alloc(1048576);
  u16* WtRK = alloc(1048576);  // contiguous: WtRK|WtRQ for merged rel GEMM
  u16* WtRQ = alloc(1048576);
  u16* Qb2  = alloc(4194304);
  u16* Kb2  = alloc(4194304);
  u16* Vb2  = alloc(4194304);
  u16* ATTb = alloc(4194304);
  u16* RKb2 = alloc(524288);
  u16* RQb2 = alloc(524288);
  float* qrk0 = (float*)(wsu + off); off += 131072;
  float* krq0 = (float*)(wsu + off); off += 131072;
  u16* bandT = alloc((size_t)NB * NH * 32 * 9 * 4096); // 75.5 MB tile-layout bias

  PrepArgs pa;
  pa.tbl = relpos; pa.gamma = gamma; pa.beta = beta; pa.e = Eb;
  pa.x = x; pa.xb = xb;
  pa.ws[0] = Wq; pa.ws[1] = Wk; pa.ws[2] = Wv; pa.ws[3] = Wo; pa.ws[4] = Wrk; pa.ws[5] = Wrq;
  pa.wd[0] = WtQ; pa.wd[1] = WtK; pa.wd[2] = WtV; pa.wd[3] = WtO; pa.wd[4] = WtRK; pa.wd[5] = WtRQ;
  prep_kernel<<<8704, 256, 0, stream>>>(pa);

  G5 g5;
  g5.bias[0] = bq; g5.bias[1] = bk; g5.bias[2] = bv; g5.bias[3] = brk; g5.bias[4] = brq;
  g5.out[0] = Qb2; g5.out[1] = Kb2; g5.out[2] = Vb2; g5.out[3] = RKb2; g5.out[4] = RQb2;
  gemm_qkvrel<<<832, 512, 0, stream>>>(xb, WtQ, Eb, WtRK, g5);

  dim3 gB(32, NH, NB);
  bias_kernel<<<gB, 256, 0, stream>>>(Qb2, Kb2, RKb2, RQb2, bandT, qrk0, krq0);

  dim3 gA(16, NH, NB); // paired q-tiles: 512 balanced blocks (XCD-remapped in-kernel)
  attn_mfma<<<gA, 256, 0, stream>>>(Qb2, Kb2, Vb2, qrk0, krq0, bandT, ATTb);

  GO goOut = {bo, out};
  dim3 gOut(8, 64); // m64: 512 blocks (%8==0) -> 2 blocks/CU
  gemm_m64<<<gOut, 256, 0, stream>>>(ATTb, WtO, goOut);
}